// Round 12
// baseline (186.877 us; speedup 1.0000x reference)
//
#include <hip/hip_runtime.h>
#include <hip/hip_bf16.h>
#include <math.h>

// Problem constants
#define S 768
#define E 512
#define H 8
#define DK 64
#define TOPK 384

typedef short bf16x8 __attribute__((ext_vector_type(8)));
typedef float f32x4 __attribute__((ext_vector_type(4)));

// ---------------------------------------------------------------------------
// fp32 <-> bf16 split helpers (round-to-nearest-even)
// ---------------------------------------------------------------------------
__device__ __forceinline__ unsigned short f2bf(float x) {
  unsigned u = __float_as_uint(x);
  unsigned r = u + 0x7FFFu + ((u >> 16) & 1u);
  return (unsigned short)(r >> 16);
}
__device__ __forceinline__ float bf2f(unsigned short h) {
  return __uint_as_float(((unsigned)h) << 16);
}
__device__ __forceinline__ void split1(float x, unsigned short& h, unsigned short& l) {
  h = f2bf(x);
  l = f2bf(x - bf2f(h));
}

// 3-term fp32-accurate bf16 MFMA: D += A*B with A=ah+al, B=bh+bl (drop al*bl)
__device__ __forceinline__ void mfma3(f32x4& d, bf16x8 ah, bf16x8 al,
                                      bf16x8 bh, bf16x8 bl) {
  d = __builtin_amdgcn_mfma_f32_16x16x32_bf16(ah, bh, d, 0, 0, 0);
  d = __builtin_amdgcn_mfma_f32_16x16x32_bf16(ah, bl, d, 0, 0, 0);
  d = __builtin_amdgcn_mfma_f32_16x16x32_bf16(al, bh, d, 0, 0, 0);
}

__device__ __forceinline__ bf16x8 ldfrag(const unsigned short* p) {
  return *reinterpret_cast<const bf16x8*>(p);
}

// ---------------------------------------------------------------------------
// prep: split x -> Xhi/Xlo; transpose+split W[k][n] -> WT[n][k] hi/lo.
// seg: 0=x(no transpose) 1=Wq 2=Wk 3=Wv 4=iqW 5=ikW 6=wpW(pad n to 64) 7=Wo
// ---------------------------------------------------------------------------
struct PrepTab {
  const float* src[8];
  unsigned short* hi[8];
  unsigned short* lo[8];
};

__global__ __launch_bounds__(256) void prep_kernel(PrepTab t) {
  const int seg = blockIdx.z;
  const int rows = (seg == 0) ? 768 : 512;
  const int cols = (seg == 5) ? 64 : ((seg == 6) ? 8 : 512);
  const int tx = (seg == 6) ? 2 : ((cols + 31) >> 5);
  const int ty = rows >> 5;
  if ((int)blockIdx.x >= tx || (int)blockIdx.y >= ty) return;
  const int r0 = blockIdx.y * 32, c0 = blockIdx.x * 32;
  const int tid = threadIdx.x;
  const int rl = tid >> 3, c4 = (tid & 7) << 2;
  const float* src = t.src[seg];
  if (seg == 0) {
    float4 v = *(const float4*)(src + (size_t)(r0 + rl) * cols + c0 + c4);
    unsigned short h[4], l[4];
    split1(v.x, h[0], l[0]); split1(v.y, h[1], l[1]);
    split1(v.z, h[2], l[2]); split1(v.w, h[3], l[3]);
    size_t off = (size_t)(r0 + rl) * cols + c0 + c4;
    *(ushort4*)(t.hi[seg] + off) = make_ushort4(h[0], h[1], h[2], h[3]);
    *(ushort4*)(t.lo[seg] + off) = make_ushort4(l[0], l[1], l[2], l[3]);
  } else {
    __shared__ float ts[32][33];
    #pragma unroll
    for (int j = 0; j < 4; ++j) {
      int c = c4 + j;
      ts[rl][c] = (c0 + c < cols) ? src[(size_t)(r0 + rl) * cols + c0 + c] : 0.0f;
    }
    __syncthreads();
    float v0 = ts[c4 + 0][rl], v1 = ts[c4 + 1][rl];
    float v2 = ts[c4 + 2][rl], v3 = ts[c4 + 3][rl];
    unsigned short h[4], l[4];
    split1(v0, h[0], l[0]); split1(v1, h[1], l[1]);
    split1(v2, h[2], l[2]); split1(v3, h[3], l[3]);
    size_t off = (size_t)(c0 + rl) * 512 + r0 + c4;
    *(ushort4*)(t.hi[seg] + off) = make_ushort4(h[0], h[1], h[2], h[3]);
    *(ushort4*)(t.lo[seg] + off) = make_ushort4(l[0], l[1], l[2], l[3]);
  }
}

// ---------------------------------------------------------------------------
// Fused projections via MFMA, 64x64 tile, INTERNAL split-K: 512 threads,
// z = K-half (256 k each). Per half: round-9 geometry (4 waves = 2x2
// quadrants of 32x32, 12 MFMA : 8 loads per k-step). z=1 posts its tile to
// LDS; z=0 adds and runs the routing epilogue. Halves run concurrently ->
// dependent-load chain halves, waves/CU doubles.
// ---------------------------------------------------------------------------
struct ProjTab {
  const unsigned short* whi[6];
  const unsigned short* wlo[6];
  const float* bias[6];
};

__global__ __launch_bounds__(512) void proj_mfma_kernel(
    const unsigned short* __restrict__ Xhi, const unsigned short* __restrict__ Xlo,
    ProjTab pt,
    unsigned short* __restrict__ Qhi, unsigned short* __restrict__ Qlo,
    unsigned short* __restrict__ Khi, unsigned short* __restrict__ Klo,
    unsigned short* __restrict__ VThi, unsigned short* __restrict__ VTlo,
    unsigned short* __restrict__ QIhi, unsigned short* __restrict__ QIlo,
    unsigned short* __restrict__ KIhi, unsigned short* __restrict__ KIlo,
    float* __restrict__ WI) {
  __shared__ float AccL[64][65];
  const int bx = blockIdx.x;
  int seg, nt;
  if (bx < 32) { seg = bx >> 3; nt = bx & 7; }
  else         { seg = 4 + (bx - 32); nt = 0; }
  const int m0 = blockIdx.y * 64;
  const int n0 = nt * 64;
  const int tid512 = threadIdx.x;
  const int z = tid512 >> 8;              // K-half
  const int tid = tid512 & 255;
  const int lane = tid & 63;
  const int wave = tid >> 6;
  const int mq = (wave >> 1) << 5;        // 0 or 32
  const int nq = (wave & 1) << 5;         // 0 or 32
  const int l15 = lane & 15;
  const int q8 = (lane >> 4) << 3;
  const int q4 = (lane >> 4) << 2;
  const unsigned short* Whi = pt.whi[seg];
  const unsigned short* Wlo = pt.wlo[seg];

  const size_t arow0 = (size_t)(m0 + mq + l15) * 512;
  const size_t arow1 = (size_t)(m0 + mq + 16 + l15) * 512;
  const size_t brow0 = (size_t)(n0 + nq + l15) * 512;
  const size_t brow1 = (size_t)(n0 + nq + 16 + l15) * 512;

  const int kbase = z << 8;
  f32x4 acc[2][2] = {};
  #pragma unroll 2
  for (int k0 = kbase; k0 < kbase + 256; k0 += 32) {
    const int ko = k0 + q8;
    bf16x8 ah0 = ldfrag(Xhi + arow0 + ko);
    bf16x8 al0 = ldfrag(Xlo + arow0 + ko);
    bf16x8 ah1 = ldfrag(Xhi + arow1 + ko);
    bf16x8 al1 = ldfrag(Xlo + arow1 + ko);
    bf16x8 bh0 = ldfrag(Whi + brow0 + ko);
    bf16x8 bl0 = ldfrag(Wlo + brow0 + ko);
    bf16x8 bh1 = ldfrag(Whi + brow1 + ko);
    bf16x8 bl1 = ldfrag(Wlo + brow1 + ko);
    mfma3(acc[0][0], ah0, al0, bh0, bl0);
    mfma3(acc[0][1], ah0, al0, bh1, bl1);
    mfma3(acc[1][0], ah1, al1, bh0, bl0);
    mfma3(acc[1][1], ah1, al1, bh1, bl1);
  }

  if (z == 1) {
    #pragma unroll
    for (int mt = 0; mt < 2; ++mt)
      #pragma unroll
      for (int ntt = 0; ntt < 2; ++ntt)
        #pragma unroll
        for (int r = 0; r < 4; ++r)
          AccL[mq + mt * 16 + q4 + r][nq + ntt * 16 + l15] = acc[mt][ntt][r];
  }
  __syncthreads();
  if (z == 0) {
    const float* bias = pt.bias[seg];
    #pragma unroll
    for (int ntt = 0; ntt < 2; ++ntt) {
      const int nloc = n0 + nq + ntt * 16 + l15;
      const float bv = (seg == 5 && nloc >= 8) ? 0.0f : bias[nloc];
      #pragma unroll
      for (int mt = 0; mt < 2; ++mt) {
        #pragma unroll
        for (int r = 0; r < 4; ++r) {
          const int m = m0 + mq + mt * 16 + q4 + r;
          const float v = acc[mt][ntt][r] +
                          AccL[mq + mt * 16 + q4 + r][nq + ntt * 16 + l15] + bv;
          unsigned short h16, l16;
          if (seg == 0) {
            split1(v, h16, l16);
            Qhi[(size_t)m * 512 + nloc] = h16;
            Qlo[(size_t)m * 512 + nloc] = l16;
          } else if (seg == 1) {
            const int hh = nloc >> 6, dd = nloc & 63;
            split1(v, h16, l16);
            Khi[((size_t)hh * S + m) * 64 + dd] = h16;
            Klo[((size_t)hh * S + m) * 64 + dd] = l16;
          } else if (seg == 2) {
            const int hh = nloc >> 6, dd = nloc & 63;
            split1(v, h16, l16);
            VThi[((size_t)hh * 64 + dd) * S + m] = h16;
            VTlo[((size_t)hh * 64 + dd) * S + m] = l16;
          } else if (seg == 3) {
            split1(v, h16, l16);
            QIhi[(size_t)m * 512 + nloc] = h16;
            QIlo[(size_t)m * 512 + nloc] = l16;
          } else if (seg == 4) {
            split1(v, h16, l16);
            KIhi[(size_t)m * 64 + nloc] = h16;
            KIlo[(size_t)m * 64 + nloc] = l16;
          } else {
            if (nloc < 8) WI[(size_t)m * 8 + nloc] = v;
          }
        }
      }
    }
  }
}

// ---------------------------------------------------------------------------
// Indexer via MFMA, INTERNAL split over heads: 512 threads, z = head-group
// (4 heads each; relu·w applied per-head, cross-group add is exact for the
// all-zero rows). 32x64 tile per block, grid (12, 24) = 288 blocks x 8 waves.
// ---------------------------------------------------------------------------
__global__ __launch_bounds__(512) void indexer_mfma_kernel(
    const unsigned short* __restrict__ QIhi, const unsigned short* __restrict__ QIlo,
    const unsigned short* __restrict__ KIhi, const unsigned short* __restrict__ KIlo,
    const float* __restrict__ WI, float* __restrict__ ISC) {
  __shared__ float wis[32][8];
  __shared__ float AccL[32][65];
  const int s0 = blockIdx.y * 32, t0 = blockIdx.x * 64;
  const int tid512 = threadIdx.x;
  const int z = tid512 >> 8;              // head-group
  const int tid = tid512 & 255;
  const int lane = tid & 63;
  const int wave = tid >> 6;
  const int mq = (wave >> 1) << 4;
  const int nqb = (wave & 1) << 5;
  const int l15 = lane & 15;
  const int q8 = (lane >> 4) << 3;
  const int q4 = (lane >> 4) << 2;
  if (tid512 < 256) wis[tid512 >> 3][tid512 & 7] = WI[(size_t)(s0 + (tid512 >> 3)) * 8 + (tid512 & 7)];
  __syncthreads();

  const size_t arow = (size_t)(s0 + mq + l15) * 512;
  const size_t brow0 = (size_t)(t0 + nqb + l15) * 64;
  const size_t brow1 = (size_t)(t0 + nqb + 16 + l15) * 64;

  float accI[2][4] = {};
  #pragma unroll
  for (int hh = 0; hh < 4; ++hh) {
    const int h = z * 4 + hh;
    f32x4 d[2] = {};
    #pragma unroll
    for (int k0 = 0; k0 < 64; k0 += 32) {
      const int ka = h * 64 + k0 + q8;
      const int kb = k0 + q8;
      bf16x8 ah = ldfrag(QIhi + arow + ka);
      bf16x8 al = ldfrag(QIlo + arow + ka);
      bf16x8 bh0 = ldfrag(KIhi + brow0 + kb);
      bf16x8 bl0 = ldfrag(KIlo + brow0 + kb);
      bf16x8 bh1 = ldfrag(KIhi + brow1 + kb);
      bf16x8 bl1 = ldfrag(KIlo + brow1 + kb);
      mfma3(d[0], ah, al, bh0, bl0);
      mfma3(d[1], ah, al, bh1, bl1);
    }
    #pragma unroll
    for (int r = 0; r < 4; ++r) {
      const float w = wis[mq + q4 + r][h];
      accI[0][r] = fmaf(fmaxf(d[0][r], 0.0f), w, accI[0][r]);
      accI[1][r] = fmaf(fmaxf(d[1][r], 0.0f), w, accI[1][r]);
    }
  }
  if (z == 1) {
    #pragma unroll
    for (int ntt = 0; ntt < 2; ++ntt)
      #pragma unroll
      for (int r = 0; r < 4; ++r)
        AccL[mq + q4 + r][nqb + ntt * 16 + l15] = accI[ntt][r];
  }
  __syncthreads();
  if (z == 0) {
    #pragma unroll
    for (int ntt = 0; ntt < 2; ++ntt)
      #pragma unroll
      for (int r = 0; r < 4; ++r)
        ISC[(size_t)(s0 + mq + q4 + r) * S + t0 + nqb + ntt * 16 + l15] =
            accI[ntt][r] + AccL[mq + q4 + r][nqb + ntt * 16 + l15];
  }
}

// ---------------------------------------------------------------------------
// Top-k via exact radix select (selection set == jax.lax.top_k stable ties).
// Emits 768-bit mask, zeroes Sum.
// ---------------------------------------------------------------------------
__global__ __launch_bounds__(256) void topk_kernel(
    const float* __restrict__ ISC, unsigned* __restrict__ Mask,
    float* __restrict__ Sum) {
  __shared__ unsigned ordv[768];
  __shared__ int hist[256];
  __shared__ int gsum[16];
  __shared__ int sc[256];
  __shared__ unsigned mw[24];
  __shared__ unsigned sh_prefix;
  __shared__ int sh_R;
  const int s = blockIdx.x;
  const int tid = threadIdx.x;
  for (int i = tid; i < 768; i += 256) {
    float f = ISC[s * 768 + i] + 0.0f;
    unsigned u = __float_as_uint(f);
    ordv[i] = (u & 0x80000000u) ? ~u : (u | 0x80000000u);
  }
  if (tid < 24) mw[tid] = 0u;
  if (tid < H) Sum[tid * S + s] = 0.0f;
  if (tid == 0) { sh_prefix = 0u; sh_R = TOPK; }
  __syncthreads();
  for (int pass = 0; pass < 4; ++pass) {
    const int shift = 24 - pass * 8;
    hist[tid] = 0;
    __syncthreads();
    const unsigned pm = (pass == 0) ? 0u : (0xFFFFFFFFu << (shift + 8));
    const unsigned pref = sh_prefix;
    for (int i = tid; i < 768; i += 256) {
      unsigned o = ordv[i];
      if ((o & pm) == pref) atomicAdd(&hist[(o >> shift) & 255], 1);
    }
    __syncthreads();
    if (tid < 16) {
      int t = 0;
      #pragma unroll
      for (int k = 0; k < 16; ++k) t += hist[tid * 16 + k];
      gsum[tid] = t;
    }
    __syncthreads();
    if (tid == 0) {
      int R = sh_R;
      int G = 0;
      int g = 15;
      for (; g > 0; --g) {
        if (G + gsum[g] >= R) break;
        G += gsum[g];
      }
      int b = 15;
      for (; b > 0; --b) {
        int c = hist[g * 16 + b];
        if (G + c >= R) break;
        G += c;
      }
      sh_prefix = sh_prefix | ((unsigned)(g * 16 + b) << shift);
      sh_R = R - G;
    }
    __syncthreads();
  }
  const unsigned thr = sh_prefix;
  const int need_eq = sh_R;
  const int base = tid * 3;
  unsigned o0 = ordv[base], o1 = ordv[base + 1], o2 = ordv[base + 2];
  int c = (o0 == thr) + (o1 == thr) + (o2 == thr);
  sc[tid] = c;
  __syncthreads();
  for (int off = 1; off < 256; off <<= 1) {
    int v = (tid >= off) ? sc[tid - off] : 0;
    __syncthreads();
    sc[tid] += v;
    __syncthreads();
  }
  int rank = sc[tid] - c;
  if (o0 > thr || (o0 == thr && rank < need_eq))
    atomicOr(&mw[base >> 5], 1u << (base & 31));
  if (o0 == thr) ++rank;
  if (o1 > thr || (o1 == thr && rank < need_eq))
    atomicOr(&mw[(base + 1) >> 5], 1u << ((base + 1) & 31));
  if (o1 == thr) ++rank;
  if (o2 > thr || (o2 == thr && rank < need_eq))
    atomicOr(&mw[(base + 2) >> 5], 1u << ((base + 2) & 31));
  __syncthreads();
  if (tid < 24) Mask[s * 24 + tid] = mw[tid];
}

// ---------------------------------------------------------------------------
// Fused masked attention via MFMA (verified correct). Block = (ks, s-tile, h).
// ---------------------------------------------------------------------------
__global__ __launch_bounds__(256) void sattn_kernel(
    const unsigned short* __restrict__ Qhi, const unsigned short* __restrict__ Qlo,
    const unsigned short* __restrict__ Khi, const unsigned short* __restrict__ Klo,
    const unsigned short* __restrict__ VThi, const unsigned short* __restrict__ VTlo,
    const unsigned* __restrict__ Mask, float* __restrict__ Opart,
    float* __restrict__ Sum) {
  __shared__ __align__(16) unsigned short Pshi[32][40];
  __shared__ __align__(16) unsigned short Pslo[32][40];
  __shared__ unsigned msk[32][6];
  __shared__ float rsumf[32];
  const int ks = blockIdx.x;
  const int s0 = blockIdx.y * 32;
  const int h  = blockIdx.z;
  const int tid = threadIdx.x;
  const int lane = tid & 63;
  const int wave = tid >> 6;
  const int l15 = lane & 15;
  const int q8 = (lane >> 4) << 3;
  const int q4 = (lane >> 4) << 2;
  const int mq = (wave >> 1) << 4;
  const int nq = (wave & 1) << 4;
  const int db = (wave & 1) << 5;

  if (tid < 192) msk[tid & 31][tid >> 5] = Mask[(size_t)(s0 + (tid & 31)) * 24 + ks * 6 + (tid >> 5)];
  if (tid < 32) rsumf[tid] = 0.0f;
  __syncthreads();

  const size_t qrow = (size_t)(s0 + mq + l15) * 512 + h * 64;
  f32x4 oacc[2] = {};
  for (int ct = 0; ct < 6; ++ct) {
    const int tch = ks * 192 + ct * 32;
    f32x4 d = {0.0f, 0.0f, 0.0f, 0.0f};
    const size_t krow = ((size_t)h * S + tch + nq + l15) * 64;
    #pragma unroll
    for (int k0 = 0; k0 < 64; k0 += 32) {
      bf16x8 ah = ldfrag(Qhi + qrow + k0 + q8);
      bf16x8 al = ldfrag(Qlo + qrow + k0 + q8);
      bf16x8 bh = ldfrag(Khi + krow + k0 + q8);
      bf16x8 bl = ldfrag(Klo + krow + k0 + q8);
      mfma3(d, ah, al, bh, bl);
    }
    const int tl = ct * 32 + nq + l15;
    float e[4];
    #pragma unroll
    for (int r = 0; r < 4; ++r) {
      const int srow = mq + q4 + r;
      const unsigned w = msk[srow][tl >> 5];
      e[r] = ((w >> (tl & 31)) & 1u) ? __expf(d[r] * 0.125f) : 0.0f;
      unsigned short h16, l16;
      split1(e[r], h16, l16);
      Pshi[srow][nq + l15] = h16;
      Pslo[srow][nq + l15] = l16;
    }
    float v0 = e[0], v1 = e[1], v2 = e[2], v3 = e[3];
    #pragma unroll
    for (int off = 1; off < 16; off <<= 1) {
      v0 += __shfl_xor(v0, off);
      v1 += __shfl_xor(v1, off);
      v2 += __shfl_xor(v2, off);
      v3 += __shfl_xor(v3, off);
    }
    if (l15 == 0) {
      atomicAdd(&rsumf[mq + q4 + 0], v0);
      atomicAdd(&rsumf[mq + q4 + 1], v1);
      atomicAdd(&rsumf[mq + q4 + 2], v2);
      atomicAdd(&rsumf[mq + q4 + 3], v3);
    }
    __syncthreads();
    bf16x8 pah = *(const bf16x8*)&Pshi[mq + l15][q8];
    bf16x8 pal = *(const bf16x8*)&Pslo[mq + l15][q8];
    #pragma unroll
    for (int dt = 0; dt < 2; ++dt) {
      const size_t vrow = ((size_t)h * 64 + db + dt * 16 + l15) * S + tch;
      bf16x8 vbh = ldfrag(VThi + vrow + q8);
      bf16x8 vbl = ldfrag(VTlo + vrow + q8);
      mfma3(oacc[dt], pah, pal, vbh, vbl);
    }
    __syncthreads();
  }
  float* Op = Opart + (size_t)ks * S * E;
  #pragma unroll
  for (int dt = 0; dt < 2; ++dt) {
    const int dd = db + dt * 16 + l15;
    #pragma unroll
    for (int r = 0; r < 4; ++r) {
      const int s = s0 + mq + q4 + r;
      Op[(size_t)s * E + h * DK + dd] = oacc[dt][r];
    }
  }
  if (tid < 32) atomicAdd(&Sum[(size_t)h * S + s0 + tid], rsumf[tid]);
}

// ---------------------------------------------------------------------------
// Combine PV partials, normalize, emit ATT as bf16 hi/lo.
// ---------------------------------------------------------------------------
__global__ __launch_bounds__(128) void combine_kernel(
    const float* __restrict__ Opart, const float* __restrict__ Sum,
    unsigned short* __restrict__ ATThi, unsigned short* __restrict__ ATTlo) {
  const int s = blockIdx.x;
  const int e = threadIdx.x * 4;
  const int h = e >> 6;
  const float inv = 1.0f / Sum[h * S + s];
  float4 o = {0.0f, 0.0f, 0.0f, 0.0f};
  #pragma unroll
  for (int x = 0; x < 4; ++x) {
    float4 p = *(const float4*)(Opart + (size_t)x * S * E + s * E + e);
    o.x += p.x; o.y += p.y; o.z += p.z; o.w += p.w;
  }
  o.x *= inv; o.y *= inv; o.z *= inv; o.w *= inv;
  unsigned short hh[4], ll[4];
  split1(o.x, hh[0], ll[0]); split1(o.y, hh[1], ll[1]);
  split1(o.z, hh[2], ll[2]); split1(o.w, hh[3], ll[3]);
  *(ushort4*)(ATThi + (size_t)s * 512 + e) = make_ushort4(hh[0], hh[1], hh[2], hh[3]);
  *(ushort4*)(ATTlo + (size_t)s * 512 + e) = make_ushort4(ll[0], ll[1], ll[2], ll[3]);
}

// ---------------------------------------------------------------------------
// Output projection via MFMA, INTERNAL split-K: 512 threads, z = K-half.
// Block = 16m x 64n (4 waves of 16x16 per half). z=1 posts to LDS, z=0
// adds + bias + stores. Grid (8, 48) = 384 blocks x 8 waves.
// ---------------------------------------------------------------------------
__global__ __launch_bounds__(512) void out_mfma_kernel(
    const unsigned short* __restrict__ Ahi, const unsigned short* __restrict__ Alo,
    const unsigned short* __restrict__ WoThi, const unsigned short* __restrict__ WoTlo,
    const float* __restrict__ bo, float* __restrict__ out) {
  __shared__ float AccL[16][65];
  const int tid512 = threadIdx.x;
  const int wave8 = tid512 >> 6;
  const int z = wave8 >> 2;
  const int wave = wave8 & 3;
  const int lane = tid512 & 63;
  const int m0 = blockIdx.y * 16;
  const int n0 = blockIdx.x * 64 + wave * 16;
  const int l15 = lane & 15;
  const int q8 = (lane >> 4) << 3;
  const int q4 = (lane >> 4) << 2;
  const size_t arow = (size_t)(m0 + l15) * 512;
  const size_t brow = (size_t)(n0 + l15) * 512;
  const int kbase = z << 8;
  f32x4 acc = {};
  #pragma unroll 2
  for (int k0 = kbase; k0 < kbase + 256; k0 += 32) {
    const int ko = k0 + q8;
    bf16x8 ah = ldfrag(Ahi + arow + ko);
    bf16x8 al = ldfrag(Alo + arow + ko);
    bf16x8 bh = ldfrag(WoThi + brow + ko);
    bf16x8 bl = ldfrag(WoTlo + brow + ko);
    mfma3(acc, ah, al, bh, bl);
  }
  if (z == 1) {
    #pragma unroll
    for (int r = 0; r < 4; ++r)
      AccL[q4 + r][wave * 16 + l15] = acc[r];
  }
  __syncthreads();
  if (z == 0) {
    const int n = n0 + l15;
    const float bv = bo[n];
    #pragma unroll
    for (int r = 0; r < 4; ++r)
      out[(size_t)(m0 + q4 + r) * 512 + n] =
          acc[r] + AccL[q4 + r][wave * 16 + l15] + bv;
  }
}

// ---------------------------------------------------------------------------
// Launch
// ---------------------------------------------------------------------------
extern "C" void kernel_launch(void* const* d_in, const int* in_sizes, int n_in,
                              void* d_out, int out_size, void* d_ws, size_t ws_size,
                              hipStream_t stream) {
  const float* x    = (const float*)d_in[0];
  const float* Wq   = (const float*)d_in[1];
  const float* bq   = (const float*)d_in[2];
  const float* Wk   = (const float*)d_in[3];
  const float* bk   = (const float*)d_in[4];
  const float* Wv   = (const float*)d_in[5];
  const float* bv   = (const float*)d_in[6];
  const float* Wo   = (const float*)d_in[7];
  const float* bo   = (const float*)d_in[8];
  const float* iqW  = (const float*)d_in[9];
  const float* iqb  = (const float*)d_in[10];
  const float* ikW  = (const float*)d_in[11];
  const float* ikb  = (const float*)d_in[12];
  const float* wpW  = (const float*)d_in[13];
  const float* wpb  = (const float*)d_in[14];

  float* ws = (float*)d_ws;
  float* WI   = ws;                         // S*H fp32
  float* ISC  = WI + S * H;                 // S*S fp32
  unsigned* Mask = (unsigned*)(ISC + S * S);  // S*24
  float* Sum  = (float*)(Mask + S * 24);    // H*S
  float* Opart = Sum + H * S;               // 4*S*E fp32
  unsigned short* u = (unsigned short*)(Opart + 4 * S * E);
  unsigned short* Xhi  = u;             u += S * E;
  unsigned short* Xlo  = u;             u += S * E;
  unsigned short* Qhi  = u;             u += S * E;
  unsigned short* Qlo  = u;             u += S * E;
  unsigned short* Khi  = u;             u += S * E;
  unsigned short* Klo  = u;             u += S * E;
  unsigned short* VThi = u;             u += S * E;
  unsigned short* VTlo = u;             u += S * E;
  unsigned short* QIhi = u;             u += S * E;
  unsigned short* QIlo = u;             u += S * E;
  unsigned short* KIhi = u;             u += S * DK;
  unsigned short* KIlo = u;             u += S * DK;
  unsigned short* ATThi = u;            u += S * E;
  unsigned short* ATTlo = u;            u += S * E;
  unsigned short* WTq_hi = u;           u += E * E;
  unsigned short* WTk_hi = u;           u += E * E;
  unsigned short* WTv_hi = u;           u += E * E;
  unsigned short* WTiq_hi = u;          u += E * E;
  unsigned short* WTik_hi = u;          u += 64 * E;
  unsigned short* WTwp_hi = u;          u += 64 * E;
  unsigned short* WTo_hi = u;           u += E * E;
  unsigned short* WTq_lo = u;           u += E * E;
  unsigned short* WTk_lo = u;           u += E * E;
  unsigned short* WTv_lo = u;           u += E * E;
  unsigned short* WTiq_lo = u;          u += E * E;
  unsigned short* WTik_lo = u;          u += 64 * E;
  unsigned short* WTwp_lo = u;          u += 64 * E;
  unsigned short* WTo_lo = u;           u += E * E;

  PrepTab prep;
  prep.src[0] = x;    prep.hi[0] = Xhi;     prep.lo[0] = Xlo;
  prep.src[1] = Wq;   prep.hi[1] = WTq_hi;  prep.lo[1] = WTq_lo;
  prep.src[2] = Wk;   prep.hi[2] = WTk_hi;  prep.lo[2] = WTk_lo;
  prep.src[3] = Wv;   prep.hi[3] = WTv_hi;  prep.lo[3] = WTv_lo;
  prep.src[4] = iqW;  prep.hi[4] = WTiq_hi; prep.lo[4] = WTiq_lo;
  prep.src[5] = ikW;  prep.hi[5] = WTik_hi; prep.lo[5] = WTik_lo;
  prep.src[6] = wpW;  prep.hi[6] = WTwp_hi; prep.lo[6] = WTwp_lo;
  prep.src[7] = Wo;   prep.hi[7] = WTo_hi;  prep.lo[7] = WTo_lo;

  ProjTab pt;
  pt.whi[0] = WTq_hi;  pt.wlo[0] = WTq_lo;  pt.bias[0] = bq;
  pt.whi[1] = WTk_hi;  pt.wlo[1] = WTk_lo;  pt.bias[1] = bk;
  pt.whi[2] = WTv_hi;  pt.wlo[2] = WTv_lo;  pt.bias[2] = bv;
  pt.whi[3] = WTiq_hi; pt.wlo[3] = WTiq_lo; pt.bias[3] = iqb;
  pt.whi[4] = WTik_hi; pt.wlo[4] = WTik_lo; pt.bias[4] = ikb;
  pt.whi[5] = WTwp_hi; pt.wlo[5] = WTwp_lo; pt.bias[5] = wpb;

  // 1) split x + transpose/split all weight matrices
  prep_kernel<<<dim3(16, 24, 8), dim3(256), 0, stream>>>(prep);
  // 2) projections via MFMA, internal split-K: 34 x 12 = 408 blocks x 8 waves
  proj_mfma_kernel<<<dim3(34, S / 64), dim3(512), 0, stream>>>(
      Xhi, Xlo, pt, Qhi, Qlo, Khi, Klo, VThi, VTlo, QIhi, QIlo, KIhi, KIlo, WI);
  // 3) indexer via MFMA, internal split-h: 12 x 24 = 288 blocks x 8 waves
  indexer_mfma_kernel<<<dim3(S / 64, S / 32), dim3(512), 0, stream>>>(
      QIhi, QIlo, KIhi, KIlo, WI, ISC);
  // 4) top-k per row (radix select; zeroes Sum)
  topk_kernel<<<dim3(S), dim3(256), 0, stream>>>(ISC, Mask, Sum);
  // 5) fused masked attention via MFMA: (4 chunks, 24 s-tiles, 8 h)
  sattn_kernel<<<dim3(4, S / 32, H), dim3(256), 0, stream>>>(
      Qhi, Qlo, Khi, Klo, VThi, VTlo, Mask, Opart, Sum);
  // 6) combine + normalize + cast ATT to bf16 hi/lo
  combine_kernel<<<dim3(S), dim3(128), 0, stream>>>(Opart, Sum, ATThi, ATTlo);
  // 7) output projection via MFMA, internal split-K: (8, 48) = 384 blocks
  out_mfma_kernel<<<dim3(8, 48), dim3(512), 0, stream>>>(
      ATThi, ATTlo, WTo_hi, WTo_lo, bo, (float*)d_out);
}

// Round 13
// 175.255 us; speedup vs baseline: 1.0663x; 1.0663x over previous
//
#include <hip/hip_runtime.h>
#include <hip/hip_bf16.h>
#include <math.h>

// Problem constants
#define S 768
#define E 512
#define H 8
#define DK 64
#define TOPK 384

typedef short bf16x8 __attribute__((ext_vector_type(8)));
typedef float f32x4 __attribute__((ext_vector_type(4)));

// ---------------------------------------------------------------------------
// fp32 <-> bf16 split helpers (round-to-nearest-even)
// ---------------------------------------------------------------------------
__device__ __forceinline__ unsigned short f2bf(float x) {
  unsigned u = __float_as_uint(x);
  unsigned r = u + 0x7FFFu + ((u >> 16) & 1u);
  return (unsigned short)(r >> 16);
}
__device__ __forceinline__ float bf2f(unsigned short h) {
  return __uint_as_float(((unsigned)h) << 16);
}
__device__ __forceinline__ void split1(float x, unsigned short& h, unsigned short& l) {
  h = f2bf(x);
  l = f2bf(x - bf2f(h));
}

// 3-term fp32-accurate bf16 MFMA: D += A*B with A=ah+al, B=bh+bl (drop al*bl)
__device__ __forceinline__ void mfma3(f32x4& d, bf16x8 ah, bf16x8 al,
                                      bf16x8 bh, bf16x8 bl) {
  d = __builtin_amdgcn_mfma_f32_16x16x32_bf16(ah, bh, d, 0, 0, 0);
  d = __builtin_amdgcn_mfma_f32_16x16x32_bf16(ah, bl, d, 0, 0, 0);
  d = __builtin_amdgcn_mfma_f32_16x16x32_bf16(al, bh, d, 0, 0, 0);
}
// 2-term (B bf16-only): D += (ah+al)*bh — used where B rounding err is safe
__device__ __forceinline__ void mfma2(f32x4& d, bf16x8 ah, bf16x8 al, bf16x8 bh) {
  d = __builtin_amdgcn_mfma_f32_16x16x32_bf16(ah, bh, d, 0, 0, 0);
  d = __builtin_amdgcn_mfma_f32_16x16x32_bf16(al, bh, d, 0, 0, 0);
}

__device__ __forceinline__ bf16x8 ldfrag(const unsigned short* p) {
  return *reinterpret_cast<const bf16x8*>(p);
}

// ---------------------------------------------------------------------------
// prep: split x -> Xhi/Xlo; transpose+split W[k][n] -> WT[n][k] hi/lo.
// ---------------------------------------------------------------------------
struct PrepTab {
  const float* src[8];
  unsigned short* hi[8];
  unsigned short* lo[8];
};

__global__ __launch_bounds__(256) void prep_kernel(PrepTab t) {
  const int seg = blockIdx.z;
  const int rows = (seg == 0) ? 768 : 512;
  const int cols = (seg == 5) ? 64 : ((seg == 6) ? 8 : 512);
  const int tx = (seg == 6) ? 2 : ((cols + 31) >> 5);
  const int ty = rows >> 5;
  if ((int)blockIdx.x >= tx || (int)blockIdx.y >= ty) return;
  const int r0 = blockIdx.y * 32, c0 = blockIdx.x * 32;
  const int tid = threadIdx.x;
  const int rl = tid >> 3, c4 = (tid & 7) << 2;
  const float* src = t.src[seg];
  if (seg == 0) {
    float4 v = *(const float4*)(src + (size_t)(r0 + rl) * cols + c0 + c4);
    unsigned short h[4], l[4];
    split1(v.x, h[0], l[0]); split1(v.y, h[1], l[1]);
    split1(v.z, h[2], l[2]); split1(v.w, h[3], l[3]);
    size_t off = (size_t)(r0 + rl) * cols + c0 + c4;
    *(ushort4*)(t.hi[seg] + off) = make_ushort4(h[0], h[1], h[2], h[3]);
    *(ushort4*)(t.lo[seg] + off) = make_ushort4(l[0], l[1], l[2], l[3]);
  } else {
    __shared__ float ts[32][33];
    #pragma unroll
    for (int j = 0; j < 4; ++j) {
      int c = c4 + j;
      ts[rl][c] = (c0 + c < cols) ? src[(size_t)(r0 + rl) * cols + c0 + c] : 0.0f;
    }
    __syncthreads();
    float v0 = ts[c4 + 0][rl], v1 = ts[c4 + 1][rl];
    float v2 = ts[c4 + 2][rl], v3 = ts[c4 + 3][rl];
    unsigned short h[4], l[4];
    split1(v0, h[0], l[0]); split1(v1, h[1], l[1]);
    split1(v2, h[2], l[2]); split1(v3, h[3], l[3]);
    size_t off = (size_t)(c0 + rl) * 512 + r0 + c4;
    *(ushort4*)(t.hi[seg] + off) = make_ushort4(h[0], h[1], h[2], h[3]);
    *(ushort4*)(t.lo[seg] + off) = make_ushort4(l[0], l[1], l[2], l[3]);
  }
}

// ---------------------------------------------------------------------------
// Fused projections via MFMA, 64x64 tile, internal split-K (512 thr),
// EXPLICIT register double-buffer: iteration k+1's 8 fragment loads issue
// before iteration k's 12 MFMAs -> loads overlap compute+latency.
// (One benign 64B overread past each array — lands in the next ws alloc.)
// ---------------------------------------------------------------------------
struct ProjTab {
  const unsigned short* whi[6];
  const unsigned short* wlo[6];
  const float* bias[6];
};

__global__ __launch_bounds__(512) void proj_mfma_kernel(
    const unsigned short* __restrict__ Xhi, const unsigned short* __restrict__ Xlo,
    ProjTab pt,
    unsigned short* __restrict__ Qhi, unsigned short* __restrict__ Qlo,
    unsigned short* __restrict__ Khi, unsigned short* __restrict__ Klo,
    unsigned short* __restrict__ VThi,
    unsigned short* __restrict__ QIhi, unsigned short* __restrict__ QIlo,
    unsigned short* __restrict__ KIhi, unsigned short* __restrict__ KIlo,
    float* __restrict__ WI) {
  __shared__ float AccL[64][65];
  const int bx = blockIdx.x;
  int seg, nt;
  if (bx < 32) { seg = bx >> 3; nt = bx & 7; }
  else         { seg = 4 + (bx - 32); nt = 0; }
  const int m0 = blockIdx.y * 64;
  const int n0 = nt * 64;
  const int tid512 = threadIdx.x;
  const int z = tid512 >> 8;
  const int tid = tid512 & 255;
  const int lane = tid & 63;
  const int wave = tid >> 6;
  const int mq = (wave >> 1) << 5;
  const int nq = (wave & 1) << 5;
  const int l15 = lane & 15;
  const int q8 = (lane >> 4) << 3;
  const int q4 = (lane >> 4) << 2;
  const unsigned short* Whi = pt.whi[seg];
  const unsigned short* Wlo = pt.wlo[seg];

  const size_t arow0 = (size_t)(m0 + mq + l15) * 512;
  const size_t arow1 = (size_t)(m0 + mq + 16 + l15) * 512;
  const size_t brow0 = (size_t)(n0 + nq + l15) * 512;
  const size_t brow1 = (size_t)(n0 + nq + 16 + l15) * 512;

  int ko = (z << 8) + q8;
  bf16x8 cah0 = ldfrag(Xhi + arow0 + ko);
  bf16x8 cal0 = ldfrag(Xlo + arow0 + ko);
  bf16x8 cah1 = ldfrag(Xhi + arow1 + ko);
  bf16x8 cal1 = ldfrag(Xlo + arow1 + ko);
  bf16x8 cbh0 = ldfrag(Whi + brow0 + ko);
  bf16x8 cbl0 = ldfrag(Wlo + brow0 + ko);
  bf16x8 cbh1 = ldfrag(Whi + brow1 + ko);
  bf16x8 cbl1 = ldfrag(Wlo + brow1 + ko);

  f32x4 acc[2][2] = {};
  #pragma unroll
  for (int it = 0; it < 8; ++it) {
    const int kn = ko + 32;
    bf16x8 nah0 = ldfrag(Xhi + arow0 + kn);
    bf16x8 nal0 = ldfrag(Xlo + arow0 + kn);
    bf16x8 nah1 = ldfrag(Xhi + arow1 + kn);
    bf16x8 nal1 = ldfrag(Xlo + arow1 + kn);
    bf16x8 nbh0 = ldfrag(Whi + brow0 + kn);
    bf16x8 nbl0 = ldfrag(Wlo + brow0 + kn);
    bf16x8 nbh1 = ldfrag(Whi + brow1 + kn);
    bf16x8 nbl1 = ldfrag(Wlo + brow1 + kn);
    mfma3(acc[0][0], cah0, cal0, cbh0, cbl0);
    mfma3(acc[0][1], cah0, cal0, cbh1, cbl1);
    mfma3(acc[1][0], cah1, cal1, cbh0, cbl0);
    mfma3(acc[1][1], cah1, cal1, cbh1, cbl1);
    cah0 = nah0; cal0 = nal0; cah1 = nah1; cal1 = nal1;
    cbh0 = nbh0; cbl0 = nbl0; cbh1 = nbh1; cbl1 = nbl1;
    ko = kn;
  }

  if (z == 1) {
    #pragma unroll
    for (int mt = 0; mt < 2; ++mt)
      #pragma unroll
      for (int ntt = 0; ntt < 2; ++ntt)
        #pragma unroll
        for (int r = 0; r < 4; ++r)
          AccL[mq + mt * 16 + q4 + r][nq + ntt * 16 + l15] = acc[mt][ntt][r];
  }
  __syncthreads();
  if (z == 0) {
    const float* bias = pt.bias[seg];
    #pragma unroll
    for (int ntt = 0; ntt < 2; ++ntt) {
      const int nloc = n0 + nq + ntt * 16 + l15;
      const float bv = (seg == 5 && nloc >= 8) ? 0.0f : bias[nloc];
      #pragma unroll
      for (int mt = 0; mt < 2; ++mt) {
        #pragma unroll
        for (int r = 0; r < 4; ++r) {
          const int m = m0 + mq + mt * 16 + q4 + r;
          const float v = acc[mt][ntt][r] +
                          AccL[mq + mt * 16 + q4 + r][nq + ntt * 16 + l15] + bv;
          unsigned short h16, l16;
          if (seg == 0) {
            split1(v, h16, l16);
            Qhi[(size_t)m * 512 + nloc] = h16;
            Qlo[(size_t)m * 512 + nloc] = l16;
          } else if (seg == 1) {
            const int hh = nloc >> 6, dd = nloc & 63;
            split1(v, h16, l16);
            Khi[((size_t)hh * S + m) * 64 + dd] = h16;
            Klo[((size_t)hh * S + m) * 64 + dd] = l16;
          } else if (seg == 2) {
            // V: hi only (PV is 2-term; V rounding err ~5e-5 on output)
            VThi[((size_t)(nloc >> 6) * 64 + (nloc & 63)) * S + m] = f2bf(v);
          } else if (seg == 3) {
            split1(v, h16, l16);
            QIhi[(size_t)m * 512 + nloc] = h16;
            QIlo[(size_t)m * 512 + nloc] = l16;
          } else if (seg == 4) {
            split1(v, h16, l16);
            KIhi[(size_t)m * 64 + nloc] = h16;
            KIlo[(size_t)m * 64 + nloc] = l16;
          } else {
            if (nloc < 8) WI[(size_t)m * 8 + nloc] = v;
          }
        }
      }
    }
  }
}

// ---------------------------------------------------------------------------
// Indexer via MFMA, internal split over heads, 3-term (ISC tie-gap ~4e-3
// forbids 2-term). Full 4-head unroll gives the scheduler all loads.
// ---------------------------------------------------------------------------
__global__ __launch_bounds__(512) void indexer_mfma_kernel(
    const unsigned short* __restrict__ QIhi, const unsigned short* __restrict__ QIlo,
    const unsigned short* __restrict__ KIhi, const unsigned short* __restrict__ KIlo,
    const float* __restrict__ WI, float* __restrict__ ISC) {
  __shared__ float wis[32][8];
  __shared__ float AccL[32][65];
  const int s0 = blockIdx.y * 32, t0 = blockIdx.x * 64;
  const int tid512 = threadIdx.x;
  const int z = tid512 >> 8;
  const int tid = tid512 & 255;
  const int lane = tid & 63;
  const int wave = tid >> 6;
  const int mq = (wave >> 1) << 4;
  const int nqb = (wave & 1) << 5;
  const int l15 = lane & 15;
  const int q8 = (lane >> 4) << 3;
  const int q4 = (lane >> 4) << 2;
  if (tid512 < 256) wis[tid512 >> 3][tid512 & 7] = WI[(size_t)(s0 + (tid512 >> 3)) * 8 + (tid512 & 7)];
  __syncthreads();

  const size_t arow = (size_t)(s0 + mq + l15) * 512;
  const size_t brow0 = (size_t)(t0 + nqb + l15) * 64;
  const size_t brow1 = (size_t)(t0 + nqb + 16 + l15) * 64;

  float accI[2][4] = {};
  #pragma unroll
  for (int hh = 0; hh < 4; ++hh) {
    const int h = z * 4 + hh;
    f32x4 d[2] = {};
    #pragma unroll
    for (int k0 = 0; k0 < 64; k0 += 32) {
      const int ka = h * 64 + k0 + q8;
      const int kb = k0 + q8;
      bf16x8 ah = ldfrag(QIhi + arow + ka);
      bf16x8 al = ldfrag(QIlo + arow + ka);
      bf16x8 bh0 = ldfrag(KIhi + brow0 + kb);
      bf16x8 bl0 = ldfrag(KIlo + brow0 + kb);
      bf16x8 bh1 = ldfrag(KIhi + brow1 + kb);
      bf16x8 bl1 = ldfrag(KIlo + brow1 + kb);
      mfma3(d[0], ah, al, bh0, bl0);
      mfma3(d[1], ah, al, bh1, bl1);
    }
    #pragma unroll
    for (int r = 0; r < 4; ++r) {
      const float w = wis[mq + q4 + r][h];
      accI[0][r] = fmaf(fmaxf(d[0][r], 0.0f), w, accI[0][r]);
      accI[1][r] = fmaf(fmaxf(d[1][r], 0.0f), w, accI[1][r]);
    }
  }
  if (z == 1) {
    #pragma unroll
    for (int ntt = 0; ntt < 2; ++ntt)
      #pragma unroll
      for (int r = 0; r < 4; ++r)
        AccL[mq + q4 + r][nqb + ntt * 16 + l15] = accI[ntt][r];
  }
  __syncthreads();
  if (z == 0) {
    #pragma unroll
    for (int ntt = 0; ntt < 2; ++ntt)
      #pragma unroll
      for (int r = 0; r < 4; ++r)
        ISC[(size_t)(s0 + mq + q4 + r) * S + t0 + nqb + ntt * 16 + l15] =
            accI[ntt][r] + AccL[mq + q4 + r][nqb + ntt * 16 + l15];
  }
}

// ---------------------------------------------------------------------------
// Top-k via exact radix select (selection set == jax.lax.top_k stable ties).
// ---------------------------------------------------------------------------
__global__ __launch_bounds__(256) void topk_kernel(
    const float* __restrict__ ISC, unsigned* __restrict__ Mask,
    float* __restrict__ Sum) {
  __shared__ unsigned ordv[768];
  __shared__ int hist[256];
  __shared__ int gsum[16];
  __shared__ int sc[256];
  __shared__ unsigned mw[24];
  __shared__ unsigned sh_prefix;
  __shared__ int sh_R;
  const int s = blockIdx.x;
  const int tid = threadIdx.x;
  for (int i = tid; i < 768; i += 256) {
    float f = ISC[s * 768 + i] + 0.0f;
    unsigned u = __float_as_uint(f);
    ordv[i] = (u & 0x80000000u) ? ~u : (u | 0x80000000u);
  }
  if (tid < 24) mw[tid] = 0u;
  if (tid < H) Sum[tid * S + s] = 0.0f;
  if (tid == 0) { sh_prefix = 0u; sh_R = TOPK; }
  __syncthreads();
  for (int pass = 0; pass < 4; ++pass) {
    const int shift = 24 - pass * 8;
    hist[tid] = 0;
    __syncthreads();
    const unsigned pm = (pass == 0) ? 0u : (0xFFFFFFFFu << (shift + 8));
    const unsigned pref = sh_prefix;
    for (int i = tid; i < 768; i += 256) {
      unsigned o = ordv[i];
      if ((o & pm) == pref) atomicAdd(&hist[(o >> shift) & 255], 1);
    }
    __syncthreads();
    if (tid < 16) {
      int t = 0;
      #pragma unroll
      for (int k = 0; k < 16; ++k) t += hist[tid * 16 + k];
      gsum[tid] = t;
    }
    __syncthreads();
    if (tid == 0) {
      int R = sh_R;
      int G = 0;
      int g = 15;
      for (; g > 0; --g) {
        if (G + gsum[g] >= R) break;
        G += gsum[g];
      }
      int b = 15;
      for (; b > 0; --b) {
        int c = hist[g * 16 + b];
        if (G + c >= R) break;
        G += c;
      }
      sh_prefix = sh_prefix | ((unsigned)(g * 16 + b) << shift);
      sh_R = R - G;
    }
    __syncthreads();
  }
  const unsigned thr = sh_prefix;
  const int need_eq = sh_R;
  const int base = tid * 3;
  unsigned o0 = ordv[base], o1 = ordv[base + 1], o2 = ordv[base + 2];
  int c = (o0 == thr) + (o1 == thr) + (o2 == thr);
  sc[tid] = c;
  __syncthreads();
  for (int off = 1; off < 256; off <<= 1) {
    int v = (tid >= off) ? sc[tid - off] : 0;
    __syncthreads();
    sc[tid] += v;
    __syncthreads();
  }
  int rank = sc[tid] - c;
  if (o0 > thr || (o0 == thr && rank < need_eq))
    atomicOr(&mw[base >> 5], 1u << (base & 31));
  if (o0 == thr) ++rank;
  if (o1 > thr || (o1 == thr && rank < need_eq))
    atomicOr(&mw[(base + 1) >> 5], 1u << ((base + 1) & 31));
  if (o1 == thr) ++rank;
  if (o2 > thr || (o2 == thr && rank < need_eq))
    atomicOr(&mw[(base + 2) >> 5], 1u << ((base + 2) & 31));
  __syncthreads();
  if (tid < 24) Mask[s * 24 + tid] = mw[tid];
}

// ---------------------------------------------------------------------------
// Fused masked attention via MFMA. QK 3-term; PV 2-term (V bf16-only).
// Q fragments hoisted out of the chunk loop.
// ---------------------------------------------------------------------------
__global__ __launch_bounds__(256) void sattn_kernel(
    const unsigned short* __restrict__ Qhi, const unsigned short* __restrict__ Qlo,
    const unsigned short* __restrict__ Khi, const unsigned short* __restrict__ Klo,
    const unsigned short* __restrict__ VThi,
    const unsigned* __restrict__ Mask, float* __restrict__ Opart,
    float* __restrict__ Sum) {
  __shared__ __align__(16) unsigned short Pshi[32][40];
  __shared__ __align__(16) unsigned short Pslo[32][40];
  __shared__ unsigned msk[32][6];
  __shared__ float rsumf[32];
  const int ks = blockIdx.x;
  const int s0 = blockIdx.y * 32;
  const int h  = blockIdx.z;
  const int tid = threadIdx.x;
  const int lane = tid & 63;
  const int wave = tid >> 6;
  const int l15 = lane & 15;
  const int q8 = (lane >> 4) << 3;
  const int q4 = (lane >> 4) << 2;
  const int mq = (wave >> 1) << 4;
  const int nq = (wave & 1) << 4;
  const int db = (wave & 1) << 5;

  if (tid < 192) msk[tid & 31][tid >> 5] = Mask[(size_t)(s0 + (tid & 31)) * 24 + ks * 6 + (tid >> 5)];
  if (tid < 32) rsumf[tid] = 0.0f;
  __syncthreads();

  const size_t qrow = (size_t)(s0 + mq + l15) * 512 + h * 64;
  bf16x8 qh0 = ldfrag(Qhi + qrow + 0 + q8);
  bf16x8 ql0 = ldfrag(Qlo + qrow + 0 + q8);
  bf16x8 qh1 = ldfrag(Qhi + qrow + 32 + q8);
  bf16x8 ql1 = ldfrag(Qlo + qrow + 32 + q8);

  f32x4 oacc[2] = {};
  for (int ct = 0; ct < 6; ++ct) {
    const int tch = ks * 192 + ct * 32;
    f32x4 d = {0.0f, 0.0f, 0.0f, 0.0f};
    const size_t krow = ((size_t)h * S + tch + nq + l15) * 64;
    {
      bf16x8 bh0 = ldfrag(Khi + krow + 0 + q8);
      bf16x8 bl0 = ldfrag(Klo + krow + 0 + q8);
      bf16x8 bh1 = ldfrag(Khi + krow + 32 + q8);
      bf16x8 bl1 = ldfrag(Klo + krow + 32 + q8);
      mfma3(d, qh0, ql0, bh0, bl0);
      mfma3(d, qh1, ql1, bh1, bl1);
    }
    const int tl = ct * 32 + nq + l15;
    float e[4];
    #pragma unroll
    for (int r = 0; r < 4; ++r) {
      const int srow = mq + q4 + r;
      const unsigned w = msk[srow][tl >> 5];
      e[r] = ((w >> (tl & 31)) & 1u) ? __expf(d[r] * 0.125f) : 0.0f;
      unsigned short h16, l16;
      split1(e[r], h16, l16);
      Pshi[srow][nq + l15] = h16;
      Pslo[srow][nq + l15] = l16;
    }
    float v0 = e[0], v1 = e[1], v2 = e[2], v3 = e[3];
    #pragma unroll
    for (int off = 1; off < 16; off <<= 1) {
      v0 += __shfl_xor(v0, off);
      v1 += __shfl_xor(v1, off);
      v2 += __shfl_xor(v2, off);
      v3 += __shfl_xor(v3, off);
    }
    if (l15 == 0) {
      atomicAdd(&rsumf[mq + q4 + 0], v0);
      atomicAdd(&rsumf[mq + q4 + 1], v1);
      atomicAdd(&rsumf[mq + q4 + 2], v2);
      atomicAdd(&rsumf[mq + q4 + 3], v3);
    }
    __syncthreads();
    bf16x8 pah = *(const bf16x8*)&Pshi[mq + l15][q8];
    bf16x8 pal = *(const bf16x8*)&Pslo[mq + l15][q8];
    #pragma unroll
    for (int dt = 0; dt < 2; ++dt) {
      const size_t vrow = ((size_t)h * 64 + db + dt * 16 + l15) * S + tch;
      bf16x8 vbh = ldfrag(VThi + vrow + q8);
      mfma2(oacc[dt], pah, pal, vbh);
    }
    __syncthreads();
  }
  float* Op = Opart + (size_t)ks * S * E;
  #pragma unroll
  for (int dt = 0; dt < 2; ++dt) {
    const int dd = db + dt * 16 + l15;
    #pragma unroll
    for (int r = 0; r < 4; ++r) {
      const int s = s0 + mq + q4 + r;
      Op[(size_t)s * E + h * DK + dd] = oacc[dt][r];
    }
  }
  if (tid < 32) atomicAdd(&Sum[(size_t)h * S + s0 + tid], rsumf[tid]);
}

// ---------------------------------------------------------------------------
// Combine PV partials, normalize, emit ATT as bf16 hi/lo.
// ---------------------------------------------------------------------------
__global__ __launch_bounds__(128) void combine_kernel(
    const float* __restrict__ Opart, const float* __restrict__ Sum,
    unsigned short* __restrict__ ATThi, unsigned short* __restrict__ ATTlo) {
  const int s = blockIdx.x;
  const int e = threadIdx.x * 4;
  const int h = e >> 6;
  const float inv = 1.0f / Sum[h * S + s];
  float4 o = {0.0f, 0.0f, 0.0f, 0.0f};
  #pragma unroll
  for (int x = 0; x < 4; ++x) {
    float4 p = *(const float4*)(Opart + (size_t)x * S * E + s * E + e);
    o.x += p.x; o.y += p.y; o.z += p.z; o.w += p.w;
  }
  o.x *= inv; o.y *= inv; o.z *= inv; o.w *= inv;
  unsigned short hh[4], ll[4];
  split1(o.x, hh[0], ll[0]); split1(o.y, hh[1], ll[1]);
  split1(o.z, hh[2], ll[2]); split1(o.w, hh[3], ll[3]);
  *(ushort4*)(ATThi + (size_t)s * 512 + e) = make_ushort4(hh[0], hh[1], hh[2], hh[3]);
  *(ushort4*)(ATTlo + (size_t)s * 512 + e) = make_ushort4(ll[0], ll[1], ll[2], ll[3]);
}

// ---------------------------------------------------------------------------
// Output projection via MFMA, 2-term (Wo bf16-only; err ~2e-5), internal
// split-K, explicit register double-buffer prefetch.
// ---------------------------------------------------------------------------
__global__ __launch_bounds__(512) void out_mfma_kernel(
    const unsigned short* __restrict__ Ahi, const unsigned short* __restrict__ Alo,
    const unsigned short* __restrict__ WoThi,
    const float* __restrict__ bo, float* __restrict__ out) {
  __shared__ float AccL[16][65];
  const int tid512 = threadIdx.x;
  const int wave8 = tid512 >> 6;
  const int z = wave8 >> 2;
  const int wave = wave8 & 3;
  const int lane = tid512 & 63;
  const int m0 = blockIdx.y * 16;
  const int n0 = blockIdx.x * 64 + wave * 16;
  const int l15 = lane & 15;
  const int q8 = (lane >> 4) << 3;
  const int q4 = (lane >> 4) << 2;
  const size_t arow = (size_t)(m0 + l15) * 512;
  const size_t brow = (size_t)(n0 + l15) * 512;
  int ko = (z << 8) + q8;
  bf16x8 cah = ldfrag(Ahi + arow + ko);
  bf16x8 cal = ldfrag(Alo + arow + ko);
  bf16x8 cbh = ldfrag(WoThi + brow + ko);
  f32x4 acc = {};
  #pragma unroll
  for (int it = 0; it < 8; ++it) {
    const int kn = ko + 32;
    bf16x8 nah = ldfrag(Ahi + arow + kn);
    bf16x8 nal = ldfrag(Alo + arow + kn);
    bf16x8 nbh = ldfrag(WoThi + brow + kn);
    mfma2(acc, cah, cal, cbh);
    cah = nah; cal = nal; cbh = nbh;
    ko = kn;
  }
  if (z == 1) {
    #pragma unroll
    for (int r = 0; r < 4; ++r)
      AccL[q4 + r][wave * 16 + l15] = acc[r];
  }
  __syncthreads();
  if (z == 0) {
    const int n = n0 + l15;
    const float bv = bo[n];
    #pragma unroll
    for (int r = 0; r < 4; ++r)
      out[(size_t)(m0 + q4 + r) * 512 + n] =
          acc[r] + AccL[q4 + r][wave * 16 + l15] + bv;
  }
}

// ---------------------------------------------------------------------------
// Launch
// ---------------------------------------------------------------------------
extern "C" void kernel_launch(void* const* d_in, const int* in_sizes, int n_in,
                              void* d_out, int out_size, void* d_ws, size_t ws_size,
                              hipStream_t stream) {
  const float* x    = (const float*)d_in[0];
  const float* Wq   = (const float*)d_in[1];
  const float* bq   = (const float*)d_in[2];
  const float* Wk   = (const float*)d_in[3];
  const float* bk   = (const float*)d_in[4];
  const float* Wv   = (const float*)d_in[5];
  const float* bv   = (const float*)d_in[6];
  const float* Wo   = (const float*)d_in[7];
  const float* bo   = (const float*)d_in[8];
  const float* iqW  = (const float*)d_in[9];
  const float* iqb  = (const float*)d_in[10];
  const float* ikW  = (const float*)d_in[11];
  const float* ikb  = (const float*)d_in[12];
  const float* wpW  = (const float*)d_in[13];
  const float* wpb  = (const float*)d_in[14];

  float* ws = (float*)d_ws;
  float* WI   = ws;                         // S*H fp32
  float* ISC  = WI + S * H;                 // S*S fp32
  unsigned* Mask = (unsigned*)(ISC + S * S);  // S*24
  float* Sum  = (float*)(Mask + S * 24);    // H*S
  float* Opart = Sum + H * S;               // 4*S*E fp32
  unsigned short* u = (unsigned short*)(Opart + 4 * S * E);
  unsigned short* Xhi  = u;             u += S * E;
  unsigned short* Xlo  = u;             u += S * E;
  unsigned short* Qhi  = u;             u += S * E;
  unsigned short* Qlo  = u;             u += S * E;
  unsigned short* Khi  = u;             u += S * E;
  unsigned short* Klo  = u;             u += S * E;
  unsigned short* VThi = u;             u += S * E;
  unsigned short* VTlo = u;             u += S * E;   // unused (kept for layout)
  unsigned short* QIhi = u;             u += S * E;
  unsigned short* QIlo = u;             u += S * E;
  unsigned short* KIhi = u;             u += S * DK;
  unsigned short* KIlo = u;             u += S * DK;
  unsigned short* ATThi = u;            u += S * E;
  unsigned short* ATTlo = u;            u += S * E;
  unsigned short* WTq_hi = u;           u += E * E;
  unsigned short* WTk_hi = u;           u += E * E;
  unsigned short* WTv_hi = u;           u += E * E;
  unsigned short* WTiq_hi = u;          u += E * E;
  unsigned short* WTik_hi = u;          u += 64 * E;
  unsigned short* WTwp_hi = u;          u += 64 * E;
  unsigned short* WTo_hi = u;           u += E * E;
  unsigned short* WTq_lo = u;           u += E * E;
  unsigned short* WTk_lo = u;           u += E * E;
  unsigned short* WTv_lo = u;           u += E * E;
  unsigned short* WTiq_lo = u;          u += E * E;
  unsigned short* WTik_lo = u;          u += 64 * E;
  unsigned short* WTwp_lo = u;          u += 64 * E;
  unsigned short* WTo_lo = u;           u += E * E;

  PrepTab prep;
  prep.src[0] = x;    prep.hi[0] = Xhi;     prep.lo[0] = Xlo;
  prep.src[1] = Wq;   prep.hi[1] = WTq_hi;  prep.lo[1] = WTq_lo;
  prep.src[2] = Wk;   prep.hi[2] = WTk_hi;  prep.lo[2] = WTk_lo;
  prep.src[3] = Wv;   prep.hi[3] = WTv_hi;  prep.lo[3] = WTv_lo;
  prep.src[4] = iqW;  prep.hi[4] = WTiq_hi; prep.lo[4] = WTiq_lo;
  prep.src[5] = ikW;  prep.hi[5] = WTik_hi; prep.lo[5] = WTik_lo;
  prep.src[6] = wpW;  prep.hi[6] = WTwp_hi; prep.lo[6] = WTwp_lo;
  prep.src[7] = Wo;   prep.hi[7] = WTo_hi;  prep.lo[7] = WTo_lo;

  ProjTab pt;
  pt.whi[0] = WTq_hi;  pt.wlo[0] = WTq_lo;  pt.bias[0] = bq;
  pt.whi[1] = WTk_hi;  pt.wlo[1] = WTk_lo;  pt.bias[1] = bk;
  pt.whi[2] = WTv_hi;  pt.wlo[2] = WTv_lo;  pt.bias[2] = bv;
  pt.whi[3] = WTiq_hi; pt.wlo[3] = WTiq_lo; pt.bias[3] = iqb;
  pt.whi[4] = WTik_hi; pt.wlo[4] = WTik_lo; pt.bias[4] = ikb;
  pt.whi[5] = WTwp_hi; pt.wlo[5] = WTwp_lo; pt.bias[5] = wpb;

  // 1) split x + transpose/split all weight matrices
  prep_kernel<<<dim3(16, 24, 8), dim3(256), 0, stream>>>(prep);
  // 2) projections via MFMA (split-K, register prefetch): 408 blocks x 8 waves
  proj_mfma_kernel<<<dim3(34, S / 64), dim3(512), 0, stream>>>(
      Xhi, Xlo, pt, Qhi, Qlo, Khi, Klo, VThi, QIhi, QIlo, KIhi, KIlo, WI);
  // 3) indexer via MFMA (split-h): 288 blocks x 8 waves
  indexer_mfma_kernel<<<dim3(S / 64, S / 32), dim3(512), 0, stream>>>(
      QIhi, QIlo, KIhi, KIlo, WI, ISC);
  // 4) top-k per row (radix select; zeroes Sum)
  topk_kernel<<<dim3(S), dim3(256), 0, stream>>>(ISC, Mask, Sum);
  // 5) fused masked attention via MFMA (QK 3-term, PV 2-term): 768 blocks
  sattn_kernel<<<dim3(4, S / 32, H), dim3(256), 0, stream>>>(
      Qhi, Qlo, Khi, Klo, VThi, Mask, Opart, Sum);
  // 6) combine + normalize + cast ATT to bf16 hi/lo
  combine_kernel<<<dim3(S), dim3(128), 0, stream>>>(Opart, Sum, ATThi, ATTlo);
  // 7) output projection via MFMA (2-term, split-K, prefetch): 384 blocks
  out_mfma_kernel<<<dim3(8, 48), dim3(512), 0, stream>>>(
      ATThi, ATTlo, WTo_hi, bo, (float*)d_out);
}

// Round 14
// 174.942 us; speedup vs baseline: 1.0682x; 1.0018x over previous
//
#include <hip/hip_runtime.h>
#include <hip/hip_bf16.h>
#include <math.h>

// Problem constants
#define S 768
#define E 512
#define H 8
#define DK 64
#define TOPK 384

typedef short bf16x8 __attribute__((ext_vector_type(8)));
typedef float f32x4 __attribute__((ext_vector_type(4)));

// ---------------------------------------------------------------------------
// fp32 <-> bf16 split helpers (round-to-nearest-even)
// ---------------------------------------------------------------------------
__device__ __forceinline__ unsigned short f2bf(float x) {
  unsigned u = __float_as_uint(x);
  unsigned r = u + 0x7FFFu + ((u >> 16) & 1u);
  return (unsigned short)(r >> 16);
}
__device__ __forceinline__ float bf2f(unsigned short h) {
  return __uint_as_float(((unsigned)h) << 16);
}
__device__ __forceinline__ void split1(float x, unsigned short& h, unsigned short& l) {
  h = f2bf(x);
  l = f2bf(x - bf2f(h));
}

// 3-term fp32-accurate bf16 MFMA: D += A*B with A=ah+al, B=bh+bl (drop al*bl)
__device__ __forceinline__ void mfma3(f32x4& d, bf16x8 ah, bf16x8 al,
                                      bf16x8 bh, bf16x8 bl) {
  d = __builtin_amdgcn_mfma_f32_16x16x32_bf16(ah, bh, d, 0, 0, 0);
  d = __builtin_amdgcn_mfma_f32_16x16x32_bf16(ah, bl, d, 0, 0, 0);
  d = __builtin_amdgcn_mfma_f32_16x16x32_bf16(al, bh, d, 0, 0, 0);
}
// 2-term (B bf16-only)
__device__ __forceinline__ void mfma2(f32x4& d, bf16x8 ah, bf16x8 al, bf16x8 bh) {
  d = __builtin_amdgcn_mfma_f32_16x16x32_bf16(ah, bh, d, 0, 0, 0);
  d = __builtin_amdgcn_mfma_f32_16x16x32_bf16(al, bh, d, 0, 0, 0);
}

__device__ __forceinline__ bf16x8 ldfrag(const unsigned short* p) {
  return *reinterpret_cast<const bf16x8*>(p);
}

// ---------------------------------------------------------------------------
// prep: split x -> Xhi/Xlo; transpose+split W[k][n] -> WT[n][k] hi/lo.
// ---------------------------------------------------------------------------
struct PrepTab {
  const float* src[8];
  unsigned short* hi[8];
  unsigned short* lo[8];
};

__global__ __launch_bounds__(256) void prep_kernel(PrepTab t) {
  const int seg = blockIdx.z;
  const int rows = (seg == 0) ? 768 : 512;
  const int cols = (seg == 5) ? 64 : ((seg == 6) ? 8 : 512);
  const int tx = (seg == 6) ? 2 : ((cols + 31) >> 5);
  const int ty = rows >> 5;
  if ((int)blockIdx.x >= tx || (int)blockIdx.y >= ty) return;
  const int r0 = blockIdx.y * 32, c0 = blockIdx.x * 32;
  const int tid = threadIdx.x;
  const int rl = tid >> 3, c4 = (tid & 7) << 2;
  const float* src = t.src[seg];
  if (seg == 0) {
    float4 v = *(const float4*)(src + (size_t)(r0 + rl) * cols + c0 + c4);
    unsigned short h[4], l[4];
    split1(v.x, h[0], l[0]); split1(v.y, h[1], l[1]);
    split1(v.z, h[2], l[2]); split1(v.w, h[3], l[3]);
    size_t off = (size_t)(r0 + rl) * cols + c0 + c4;
    *(ushort4*)(t.hi[seg] + off) = make_ushort4(h[0], h[1], h[2], h[3]);
    *(ushort4*)(t.lo[seg] + off) = make_ushort4(l[0], l[1], l[2], l[3]);
  } else {
    __shared__ float ts[32][33];
    #pragma unroll
    for (int j = 0; j < 4; ++j) {
      int c = c4 + j;
      ts[rl][c] = (c0 + c < cols) ? src[(size_t)(r0 + rl) * cols + c0 + c] : 0.0f;
    }
    __syncthreads();
    float v0 = ts[c4 + 0][rl], v1 = ts[c4 + 1][rl];
    float v2 = ts[c4 + 2][rl], v3 = ts[c4 + 3][rl];
    unsigned short h[4], l[4];
    split1(v0, h[0], l[0]); split1(v1, h[1], l[1]);
    split1(v2, h[2], l[2]); split1(v3, h[3], l[3]);
    size_t off = (size_t)(c0 + rl) * 512 + r0 + c4;
    *(ushort4*)(t.hi[seg] + off) = make_ushort4(h[0], h[1], h[2], h[3]);
    *(ushort4*)(t.lo[seg] + off) = make_ushort4(l[0], l[1], l[2], l[3]);
  }
}

// ---------------------------------------------------------------------------
// Fused projections via MFMA, 64x64 tile, internal split-K (512 thr),
// explicit register double-buffer prefetch (unchanged from round 13).
// ---------------------------------------------------------------------------
struct ProjTab {
  const unsigned short* whi[6];
  const unsigned short* wlo[6];
  const float* bias[6];
};

__global__ __launch_bounds__(512) void proj_mfma_kernel(
    const unsigned short* __restrict__ Xhi, const unsigned short* __restrict__ Xlo,
    ProjTab pt,
    unsigned short* __restrict__ Qhi, unsigned short* __restrict__ Qlo,
    unsigned short* __restrict__ Khi, unsigned short* __restrict__ Klo,
    unsigned short* __restrict__ VThi,
    unsigned short* __restrict__ QIhi, unsigned short* __restrict__ QIlo,
    unsigned short* __restrict__ KIhi, unsigned short* __restrict__ KIlo,
    float* __restrict__ WI) {
  __shared__ float AccL[64][65];
  const int bx = blockIdx.x;
  int seg, nt;
  if (bx < 32) { seg = bx >> 3; nt = bx & 7; }
  else         { seg = 4 + (bx - 32); nt = 0; }
  const int m0 = blockIdx.y * 64;
  const int n0 = nt * 64;
  const int tid512 = threadIdx.x;
  const int z = tid512 >> 8;
  const int tid = tid512 & 255;
  const int lane = tid & 63;
  const int wave = tid >> 6;
  const int mq = (wave >> 1) << 5;
  const int nq = (wave & 1) << 5;
  const int l15 = lane & 15;
  const int q8 = (lane >> 4) << 3;
  const int q4 = (lane >> 4) << 2;
  const unsigned short* Whi = pt.whi[seg];
  const unsigned short* Wlo = pt.wlo[seg];

  const size_t arow0 = (size_t)(m0 + mq + l15) * 512;
  const size_t arow1 = (size_t)(m0 + mq + 16 + l15) * 512;
  const size_t brow0 = (size_t)(n0 + nq + l15) * 512;
  const size_t brow1 = (size_t)(n0 + nq + 16 + l15) * 512;

  int ko = (z << 8) + q8;
  bf16x8 cah0 = ldfrag(Xhi + arow0 + ko);
  bf16x8 cal0 = ldfrag(Xlo + arow0 + ko);
  bf16x8 cah1 = ldfrag(Xhi + arow1 + ko);
  bf16x8 cal1 = ldfrag(Xlo + arow1 + ko);
  bf16x8 cbh0 = ldfrag(Whi + brow0 + ko);
  bf16x8 cbl0 = ldfrag(Wlo + brow0 + ko);
  bf16x8 cbh1 = ldfrag(Whi + brow1 + ko);
  bf16x8 cbl1 = ldfrag(Wlo + brow1 + ko);

  f32x4 acc[2][2] = {};
  #pragma unroll
  for (int it = 0; it < 8; ++it) {
    const int kn = ko + 32;
    bf16x8 nah0 = ldfrag(Xhi + arow0 + kn);
    bf16x8 nal0 = ldfrag(Xlo + arow0 + kn);
    bf16x8 nah1 = ldfrag(Xhi + arow1 + kn);
    bf16x8 nal1 = ldfrag(Xlo + arow1 + kn);
    bf16x8 nbh0 = ldfrag(Whi + brow0 + kn);
    bf16x8 nbl0 = ldfrag(Wlo + brow0 + kn);
    bf16x8 nbh1 = ldfrag(Whi + brow1 + kn);
    bf16x8 nbl1 = ldfrag(Wlo + brow1 + kn);
    mfma3(acc[0][0], cah0, cal0, cbh0, cbl0);
    mfma3(acc[0][1], cah0, cal0, cbh1, cbl1);
    mfma3(acc[1][0], cah1, cal1, cbh0, cbl0);
    mfma3(acc[1][1], cah1, cal1, cbh1, cbl1);
    cah0 = nah0; cal0 = nal0; cah1 = nah1; cal1 = nal1;
    cbh0 = nbh0; cbl0 = nbl0; cbh1 = nbh1; cbl1 = nbl1;
    ko = kn;
  }

  if (z == 1) {
    #pragma unroll
    for (int mt = 0; mt < 2; ++mt)
      #pragma unroll
      for (int ntt = 0; ntt < 2; ++ntt)
        #pragma unroll
        for (int r = 0; r < 4; ++r)
          AccL[mq + mt * 16 + q4 + r][nq + ntt * 16 + l15] = acc[mt][ntt][r];
  }
  __syncthreads();
  if (z == 0) {
    const float* bias = pt.bias[seg];
    #pragma unroll
    for (int ntt = 0; ntt < 2; ++ntt) {
      const int nloc = n0 + nq + ntt * 16 + l15;
      const float bv = (seg == 5 && nloc >= 8) ? 0.0f : bias[nloc];
      #pragma unroll
      for (int mt = 0; mt < 2; ++mt) {
        #pragma unroll
        for (int r = 0; r < 4; ++r) {
          const int m = m0 + mq + mt * 16 + q4 + r;
          const float v = acc[mt][ntt][r] +
                          AccL[mq + mt * 16 + q4 + r][nq + ntt * 16 + l15] + bv;
          unsigned short h16, l16;
          if (seg == 0) {
            split1(v, h16, l16);
            Qhi[(size_t)m * 512 + nloc] = h16;
            Qlo[(size_t)m * 512 + nloc] = l16;
          } else if (seg == 1) {
            const int hh = nloc >> 6, dd = nloc & 63;
            split1(v, h16, l16);
            Khi[((size_t)hh * S + m) * 64 + dd] = h16;
            Klo[((size_t)hh * S + m) * 64 + dd] = l16;
          } else if (seg == 2) {
            VThi[((size_t)(nloc >> 6) * 64 + (nloc & 63)) * S + m] = f2bf(v);
          } else if (seg == 3) {
            split1(v, h16, l16);
            QIhi[(size_t)m * 512 + nloc] = h16;
            QIlo[(size_t)m * 512 + nloc] = l16;
          } else if (seg == 4) {
            split1(v, h16, l16);
            KIhi[(size_t)m * 64 + nloc] = h16;
            KIlo[(size_t)m * 64 + nloc] = l16;
          } else {
            if (nloc < 8) WI[(size_t)m * 8 + nloc] = v;
          }
        }
      }
    }
  }
}

// ---------------------------------------------------------------------------
// Indexer via MFMA, internal split over heads. KI fragments are head-
// invariant -> hoisted out of the head loop (held in registers).
// ---------------------------------------------------------------------------
__global__ __launch_bounds__(512) void indexer_mfma_kernel(
    const unsigned short* __restrict__ QIhi, const unsigned short* __restrict__ QIlo,
    const unsigned short* __restrict__ KIhi, const unsigned short* __restrict__ KIlo,
    const float* __restrict__ WI, float* __restrict__ ISC) {
  __shared__ float wis[32][8];
  __shared__ float AccL[32][65];
  const int s0 = blockIdx.y * 32, t0 = blockIdx.x * 64;
  const int tid512 = threadIdx.x;
  const int z = tid512 >> 8;
  const int tid = tid512 & 255;
  const int lane = tid & 63;
  const int wave = tid >> 6;
  const int mq = (wave >> 1) << 4;
  const int nqb = (wave & 1) << 5;
  const int l15 = lane & 15;
  const int q8 = (lane >> 4) << 3;
  const int q4 = (lane >> 4) << 2;
  if (tid512 < 256) wis[tid512 >> 3][tid512 & 7] = WI[(size_t)(s0 + (tid512 >> 3)) * 8 + (tid512 & 7)];
  __syncthreads();

  const size_t arow = (size_t)(s0 + mq + l15) * 512;
  const size_t brow0 = (size_t)(t0 + nqb + l15) * 64;
  const size_t brow1 = (size_t)(t0 + nqb + 16 + l15) * 64;

  // hoisted head-invariant KI fragments
  bf16x8 kfh[2][2], kfl[2][2];
  #pragma unroll
  for (int kk = 0; kk < 2; ++kk) {
    const int kb = kk * 32 + q8;
    kfh[kk][0] = ldfrag(KIhi + brow0 + kb);
    kfl[kk][0] = ldfrag(KIlo + brow0 + kb);
    kfh[kk][1] = ldfrag(KIhi + brow1 + kb);
    kfl[kk][1] = ldfrag(KIlo + brow1 + kb);
  }

  float accI[2][4] = {};
  #pragma unroll
  for (int hh = 0; hh < 4; ++hh) {
    const int h = z * 4 + hh;
    f32x4 d[2] = {};
    #pragma unroll
    for (int kk = 0; kk < 2; ++kk) {
      const int ka = h * 64 + kk * 32 + q8;
      bf16x8 ah = ldfrag(QIhi + arow + ka);
      bf16x8 al = ldfrag(QIlo + arow + ka);
      mfma3(d[0], ah, al, kfh[kk][0], kfl[kk][0]);
      mfma3(d[1], ah, al, kfh[kk][1], kfl[kk][1]);
    }
    #pragma unroll
    for (int r = 0; r < 4; ++r) {
      const float w = wis[mq + q4 + r][h];
      accI[0][r] = fmaf(fmaxf(d[0][r], 0.0f), w, accI[0][r]);
      accI[1][r] = fmaf(fmaxf(d[1][r], 0.0f), w, accI[1][r]);
    }
  }
  if (z == 1) {
    #pragma unroll
    for (int ntt = 0; ntt < 2; ++ntt)
      #pragma unroll
      for (int r = 0; r < 4; ++r)
        AccL[mq + q4 + r][nqb + ntt * 16 + l15] = accI[ntt][r];
  }
  __syncthreads();
  if (z == 0) {
    #pragma unroll
    for (int ntt = 0; ntt < 2; ++ntt)
      #pragma unroll
      for (int r = 0; r < 4; ++r)
        ISC[(size_t)(s0 + mq + q4 + r) * S + t0 + nqb + ntt * 16 + l15] =
            accI[ntt][r] + AccL[mq + q4 + r][nqb + ntt * 16 + l15];
  }
}

// ---------------------------------------------------------------------------
// Top-k via exact radix select. Also zeroes Sum and this row of ATTacc
// (both consumed downstream by sattn's atomics).
// ---------------------------------------------------------------------------
__global__ __launch_bounds__(256) void topk_kernel(
    const float* __restrict__ ISC, unsigned* __restrict__ Mask,
    float* __restrict__ Sum, float* __restrict__ ATTacc) {
  __shared__ unsigned ordv[768];
  __shared__ int hist[256];
  __shared__ int gsum[16];
  __shared__ int sc[256];
  __shared__ unsigned mw[24];
  __shared__ unsigned sh_prefix;
  __shared__ int sh_R;
  const int s = blockIdx.x;
  const int tid = threadIdx.x;
  for (int i = tid; i < 768; i += 256) {
    float f = ISC[s * 768 + i] + 0.0f;
    unsigned u = __float_as_uint(f);
    ordv[i] = (u & 0x80000000u) ? ~u : (u | 0x80000000u);
  }
  {
    const float4 z4 = {0.0f, 0.0f, 0.0f, 0.0f};
    if (tid < 128) *(float4*)(ATTacc + (size_t)s * 512 + tid * 4) = z4;
  }
  if (tid < 24) mw[tid] = 0u;
  if (tid < H) Sum[tid * S + s] = 0.0f;
  if (tid == 0) { sh_prefix = 0u; sh_R = TOPK; }
  __syncthreads();
  for (int pass = 0; pass < 4; ++pass) {
    const int shift = 24 - pass * 8;
    hist[tid] = 0;
    __syncthreads();
    const unsigned pm = (pass == 0) ? 0u : (0xFFFFFFFFu << (shift + 8));
    const unsigned pref = sh_prefix;
    for (int i = tid; i < 768; i += 256) {
      unsigned o = ordv[i];
      if ((o & pm) == pref) atomicAdd(&hist[(o >> shift) & 255], 1);
    }
    __syncthreads();
    if (tid < 16) {
      int t = 0;
      #pragma unroll
      for (int k = 0; k < 16; ++k) t += hist[tid * 16 + k];
      gsum[tid] = t;
    }
    __syncthreads();
    if (tid == 0) {
      int R = sh_R;
      int G = 0;
      int g = 15;
      for (; g > 0; --g) {
        if (G + gsum[g] >= R) break;
        G += gsum[g];
      }
      int b = 15;
      for (; b > 0; --b) {
        int c = hist[g * 16 + b];
        if (G + c >= R) break;
        G += c;
      }
      sh_prefix = sh_prefix | ((unsigned)(g * 16 + b) << shift);
      sh_R = R - G;
    }
    __syncthreads();
  }
  const unsigned thr = sh_prefix;
  const int need_eq = sh_R;
  const int base = tid * 3;
  unsigned o0 = ordv[base], o1 = ordv[base + 1], o2 = ordv[base + 2];
  int c = (o0 == thr) + (o1 == thr) + (o2 == thr);
  sc[tid] = c;
  __syncthreads();
  for (int off = 1; off < 256; off <<= 1) {
    int v = (tid >= off) ? sc[tid - off] : 0;
    __syncthreads();
    sc[tid] += v;
    __syncthreads();
  }
  int rank = sc[tid] - c;
  if (o0 > thr || (o0 == thr && rank < need_eq))
    atomicOr(&mw[base >> 5], 1u << (base & 31));
  if (o0 == thr) ++rank;
  if (o1 > thr || (o1 == thr && rank < need_eq))
    atomicOr(&mw[(base + 1) >> 5], 1u << ((base + 1) & 31));
  if (o1 == thr) ++rank;
  if (o2 > thr || (o2 == thr && rank < need_eq))
    atomicOr(&mw[(base + 2) >> 5], 1u << ((base + 2) & 31));
  __syncthreads();
  if (tid < 24) Mask[s * 24 + tid] = mw[tid];
}

// ---------------------------------------------------------------------------
// Fused masked attention via MFMA. QK 3-term; PV 2-term. Partial O goes
// directly into ATTacc via fp32 atomicAdd (zeroed by topk) — no Opart,
// no combine kernel.
// ---------------------------------------------------------------------------
__global__ __launch_bounds__(256) void sattn_kernel(
    const unsigned short* __restrict__ Qhi, const unsigned short* __restrict__ Qlo,
    const unsigned short* __restrict__ Khi, const unsigned short* __restrict__ Klo,
    const unsigned short* __restrict__ VThi,
    const unsigned* __restrict__ Mask, float* __restrict__ ATTacc,
    float* __restrict__ Sum) {
  __shared__ __align__(16) unsigned short Pshi[32][40];
  __shared__ __align__(16) unsigned short Pslo[32][40];
  __shared__ unsigned msk[32][6];
  __shared__ float rsumf[32];
  const int ks = blockIdx.x;
  const int s0 = blockIdx.y * 32;
  const int h  = blockIdx.z;
  const int tid = threadIdx.x;
  const int lane = tid & 63;
  const int wave = tid >> 6;
  const int l15 = lane & 15;
  const int q8 = (lane >> 4) << 3;
  const int q4 = (lane >> 4) << 2;
  const int mq = (wave >> 1) << 4;
  const int nq = (wave & 1) << 4;
  const int db = (wave & 1) << 5;

  if (tid < 192) msk[tid & 31][tid >> 5] = Mask[(size_t)(s0 + (tid & 31)) * 24 + ks * 6 + (tid >> 5)];
  if (tid < 32) rsumf[tid] = 0.0f;
  __syncthreads();

  const size_t qrow = (size_t)(s0 + mq + l15) * 512 + h * 64;
  bf16x8 qh0 = ldfrag(Qhi + qrow + 0 + q8);
  bf16x8 ql0 = ldfrag(Qlo + qrow + 0 + q8);
  bf16x8 qh1 = ldfrag(Qhi + qrow + 32 + q8);
  bf16x8 ql1 = ldfrag(Qlo + qrow + 32 + q8);

  f32x4 oacc[2] = {};
  for (int ct = 0; ct < 6; ++ct) {
    const int tch = ks * 192 + ct * 32;
    f32x4 d = {0.0f, 0.0f, 0.0f, 0.0f};
    const size_t krow = ((size_t)h * S + tch + nq + l15) * 64;
    {
      bf16x8 bh0 = ldfrag(Khi + krow + 0 + q8);
      bf16x8 bl0 = ldfrag(Klo + krow + 0 + q8);
      bf16x8 bh1 = ldfrag(Khi + krow + 32 + q8);
      bf16x8 bl1 = ldfrag(Klo + krow + 32 + q8);
      mfma3(d, qh0, ql0, bh0, bl0);
      mfma3(d, qh1, ql1, bh1, bl1);
    }
    const int tl = ct * 32 + nq + l15;
    float e[4];
    #pragma unroll
    for (int r = 0; r < 4; ++r) {
      const int srow = mq + q4 + r;
      const unsigned w = msk[srow][tl >> 5];
      e[r] = ((w >> (tl & 31)) & 1u) ? __expf(d[r] * 0.125f) : 0.0f;
      unsigned short h16, l16;
      split1(e[r], h16, l16);
      Pshi[srow][nq + l15] = h16;
      Pslo[srow][nq + l15] = l16;
    }
    float v0 = e[0], v1 = e[1], v2 = e[2], v3 = e[3];
    #pragma unroll
    for (int off = 1; off < 16; off <<= 1) {
      v0 += __shfl_xor(v0, off);
      v1 += __shfl_xor(v1, off);
      v2 += __shfl_xor(v2, off);
      v3 += __shfl_xor(v3, off);
    }
    if (l15 == 0) {
      atomicAdd(&rsumf[mq + q4 + 0], v0);
      atomicAdd(&rsumf[mq + q4 + 1], v1);
      atomicAdd(&rsumf[mq + q4 + 2], v2);
      atomicAdd(&rsumf[mq + q4 + 3], v3);
    }
    __syncthreads();
    bf16x8 pah = *(const bf16x8*)&Pshi[mq + l15][q8];
    bf16x8 pal = *(const bf16x8*)&Pslo[mq + l15][q8];
    #pragma unroll
    for (int dt = 0; dt < 2; ++dt) {
      const size_t vrow = ((size_t)h * 64 + db + dt * 16 + l15) * S + tch;
      bf16x8 vbh = ldfrag(VThi + vrow + q8);
      mfma2(oacc[dt], pah, pal, vbh);
    }
    __syncthreads();
  }
  #pragma unroll
  for (int dt = 0; dt < 2; ++dt) {
    const int dd = db + dt * 16 + l15;
    #pragma unroll
    for (int r = 0; r < 4; ++r) {
      const int s = s0 + mq + q4 + r;
      atomicAdd(&ATTacc[(size_t)s * E + h * DK + dd], oacc[dt][r]);
    }
  }
  if (tid < 32) atomicAdd(&Sum[(size_t)h * S + s0 + tid], rsumf[tid]);
}

// ---------------------------------------------------------------------------
// Output projection via MFMA, 2-term, internal split-K, register prefetch.
// Reads fp32 ATTacc + Sum; normalize + bf16-split happen in-register (the
// combine kernel is gone). ivs[16][8] = 1/Sum staged in LDS.
// ---------------------------------------------------------------------------
__global__ __launch_bounds__(512) void out_mfma_kernel(
    const float* __restrict__ ATTacc, const float* __restrict__ Sum,
    const unsigned short* __restrict__ WoThi,
    const float* __restrict__ bo, float* __restrict__ out) {
  __shared__ float AccL[16][65];
  __shared__ float ivs[16][8];
  const int tid512 = threadIdx.x;
  const int wave8 = tid512 >> 6;
  const int z = wave8 >> 2;
  const int wave = wave8 & 3;
  const int lane = tid512 & 63;
  const int m0 = blockIdx.y * 16;
  const int n0 = blockIdx.x * 64 + wave * 16;
  const int l15 = lane & 15;
  const int q8 = (lane >> 4) << 3;
  const int q4 = (lane >> 4) << 2;
  if (tid512 < 128) {
    const int r = tid512 >> 3, hh = tid512 & 7;
    ivs[r][hh] = 1.0f / Sum[(size_t)hh * S + m0 + r];
  }
  __syncthreads();
  const size_t arow = (size_t)(m0 + l15) * 512;
  const size_t brow = (size_t)(n0 + l15) * 512;
  int ko = (z << 8) + q8;
  bf16x8 cah, cal;
  {
    const float inv0 = ivs[l15][(ko >> 6) & 7];
    float4 a = *(const float4*)(ATTacc + arow + ko);
    float4 b = *(const float4*)(ATTacc + arow + ko + 4);
    float v[8] = {a.x, a.y, a.z, a.w, b.x, b.y, b.z, b.w};
    #pragma unroll
    for (int i = 0; i < 8; ++i) {
      unsigned short hh, ll;
      split1(v[i] * inv0, hh, ll);
      cah[i] = (short)hh; cal[i] = (short)ll;
    }
  }
  bf16x8 cbh = ldfrag(WoThi + brow + ko);
  f32x4 acc = {};
  #pragma unroll
  for (int it = 0; it < 8; ++it) {
    const int kn = ko + 32;
    float4 na = *(const float4*)(ATTacc + arow + kn);       // benign overread
    float4 nb = *(const float4*)(ATTacc + arow + kn + 4);   //  on last iter
    bf16x8 nbh = ldfrag(WoThi + brow + kn);
    mfma2(acc, cah, cal, cbh);
    const float invn = ivs[l15][(kn >> 6) & 7];
    float v[8] = {na.x, na.y, na.z, na.w, nb.x, nb.y, nb.z, nb.w};
    #pragma unroll
    for (int i = 0; i < 8; ++i) {
      unsigned short hh, ll;
      split1(v[i] * invn, hh, ll);
      cah[i] = (short)hh; cal[i] = (short)ll;
    }
    cbh = nbh;
    ko = kn;
  }
  if (z == 1) {
    #pragma unroll
    for (int r = 0; r < 4; ++r)
      AccL[q4 + r][wave * 16 + l15] = acc[r];
  }
  __syncthreads();
  if (z == 0) {
    const int n = n0 + l15;
    const float bv = bo[n];
    #pragma unroll
    for (int r = 0; r < 4; ++r)
      out[(size_t)(m0 + q4 + r) * 512 + n] =
          acc[r] + AccL[q4 + r][wave * 16 + l15] + bv;
  }
}

// ---------------------------------------------------------------------------
// Launch
// ---------------------------------------------------------------------------
extern "C" void kernel_launch(void* const* d_in, const int* in_sizes, int n_in,
                              void* d_out, int out_size, void* d_ws, size_t ws_size,
                              hipStream_t stream) {
  const float* x    = (const float*)d_in[0];
  const float* Wq   = (const float*)d_in[1];
  const float* bq   = (const float*)d_in[2];
  const float* Wk   = (const float*)d_in[3];
  const float* bk   = (const float*)d_in[4];
  const float* Wv   = (const float*)d_in[5];
  const float* bv   = (const float*)d_in[6];
  const float* Wo   = (const float*)d_in[7];
  const float* bo   = (const float*)d_in[8];
  const float* iqW  = (const float*)d_in[9];
  const float* iqb  = (const float*)d_in[10];
  const float* ikW  = (const float*)d_in[11];
  const float* ikb  = (const float*)d_in[12];
  const float* wpW  = (const float*)d_in[13];
  const float* wpb  = (const float*)d_in[14];

  float* ws = (float*)d_ws;
  float* WI   = ws;                         // S*H fp32
  float* ISC  = WI + S * H;                 // S*S fp32
  unsigned* Mask = (unsigned*)(ISC + S * S);  // S*24
  float* Sum  = (float*)(Mask + S * 24);    // H*S
  float* ATTacc = Sum + H * S;              // S*E fp32 (atomic accumulator)
  unsigned short* u = (unsigned short*)(ATTacc + S * E);
  unsigned short* Xhi  = u;             u += S * E;
  unsigned short* Xlo  = u;             u += S * E;
  unsigned short* Qhi  = u;             u += S * E;
  unsigned short* Qlo  = u;             u += S * E;
  unsigned short* Khi  = u;             u += S * E;
  unsigned short* Klo  = u;             u += S * E;
  unsigned short* VThi = u;             u += S * E;
  unsigned short* QIhi = u;             u += S * E;
  unsigned short* QIlo = u;             u += S * E;
  unsigned short* KIhi = u;             u += S * DK;
  unsigned short* KIlo = u;             u += S * DK;
  unsigned short* WTq_hi = u;           u += E * E;
  unsigned short* WTk_hi = u;           u += E * E;
  unsigned short* WTv_hi = u;           u += E * E;
  unsigned short* WTiq_hi = u;          u += E * E;
  unsigned short* WTik_hi = u;          u += 64 * E;
  unsigned short* WTwp_hi = u;          u += 64 * E;
  unsigned short* WTo_hi = u;           u += E * E;
  unsigned short* WTq_lo = u;           u += E * E;
  unsigned short* WTk_lo = u;           u += E * E;
  unsigned short* WTv_lo = u;           u += E * E;
  unsigned short* WTiq_lo = u;          u += E * E;
  unsigned short* WTik_lo = u;          u += 64 * E;
  unsigned short* WTwp_lo = u;          u += 64 * E;
  unsigned short* WTo_lo = u;           u += E * E;

  PrepTab prep;
  prep.src[0] = x;    prep.hi[0] = Xhi;     prep.lo[0] = Xlo;
  prep.src[1] = Wq;   prep.hi[1] = WTq_hi;  prep.lo[1] = WTq_lo;
  prep.src[2] = Wk;   prep.hi[2] = WTk_hi;  prep.lo[2] = WTk_lo;
  prep.src[3] = Wv;   prep.hi[3] = WTv_hi;  prep.lo[3] = WTv_lo;
  prep.src[4] = iqW;  prep.hi[4] = WTiq_hi; prep.lo[4] = WTiq_lo;
  prep.src[5] = ikW;  prep.hi[5] = WTik_hi; prep.lo[5] = WTik_lo;
  prep.src[6] = wpW;  prep.hi[6] = WTwp_hi; prep.lo[6] = WTwp_lo;
  prep.src[7] = Wo;   prep.hi[7] = WTo_hi;  prep.lo[7] = WTo_lo;

  ProjTab pt;
  pt.whi[0] = WTq_hi;  pt.wlo[0] = WTq_lo;  pt.bias[0] = bq;
  pt.whi[1] = WTk_hi;  pt.wlo[1] = WTk_lo;  pt.bias[1] = bk;
  pt.whi[2] = WTv_hi;  pt.wlo[2] = WTv_lo;  pt.bias[2] = bv;
  pt.whi[3] = WTiq_hi; pt.wlo[3] = WTiq_lo; pt.bias[3] = iqb;
  pt.whi[4] = WTik_hi; pt.wlo[4] = WTik_lo; pt.bias[4] = ikb;
  pt.whi[5] = WTwp_hi; pt.wlo[5] = WTwp_lo; pt.bias[5] = wpb;

  // 1) split x + transpose/split all weight matrices
  prep_kernel<<<dim3(16, 24, 8), dim3(256), 0, stream>>>(prep);
  // 2) projections via MFMA (split-K, register prefetch)
  proj_mfma_kernel<<<dim3(34, S / 64), dim3(512), 0, stream>>>(
      Xhi, Xlo, pt, Qhi, Qlo, Khi, Klo, VThi, QIhi, QIlo, KIhi, KIlo, WI);
  // 3) indexer via MFMA (split-h, hoisted KI fragments)
  indexer_mfma_kernel<<<dim3(S / 64, S / 32), dim3(512), 0, stream>>>(
      QIhi, QIlo, KIhi, KIlo, WI, ISC);
  // 4) top-k per row (radix select; zeroes Sum and ATTacc)
  topk_kernel<<<dim3(S), dim3(256), 0, stream>>>(ISC, Mask, Sum, ATTacc);
  // 5) fused masked attention via MFMA -> fp32 atomics into ATTacc
  sattn_kernel<<<dim3(4, S / 32, H), dim3(256), 0, stream>>>(
      Qhi, Qlo, Khi, Klo, VThi, Mask, ATTacc, Sum);
  // 6) output projection (reads ATTacc+Sum; normalize+split in-register)
  out_mfma_kernel<<<dim3(8, 48), dim3(512), 0, stream>>>(
      ATTacc, Sum, WTo_hi, bo, (float*)d_out);
}

// Round 15
// 157.167 us; speedup vs baseline: 1.1890x; 1.1131x over previous
//
#include <hip/hip_runtime.h>
#include <hip/hip_bf16.h>
#include <math.h>

// Problem constants
#define S 768
#define E 512
#define H 8
#define DK 64
#define TOPK 384

typedef short bf16x8 __attribute__((ext_vector_type(8)));
typedef float f32x4 __attribute__((ext_vector_type(4)));

// ---------------------------------------------------------------------------
// fp32 <-> bf16 split helpers (round-to-nearest-even)
// ---------------------------------------------------------------------------
__device__ __forceinline__ unsigned short f2bf(float x) {
  unsigned u = __float_as_uint(x);
  unsigned r = u + 0x7FFFu + ((u >> 16) & 1u);
  return (unsigned short)(r >> 16);
}
__device__ __forceinline__ float bf2f(unsigned short h) {
  return __uint_as_float(((unsigned)h) << 16);
}
__device__ __forceinline__ void split1(float x, unsigned short& h, unsigned short& l) {
  h = f2bf(x);
  l = f2bf(x - bf2f(h));
}

// 3-term fp32-accurate bf16 MFMA: D += A*B with A=ah+al, B=bh+bl (drop al*bl)
__device__ __forceinline__ void mfma3(f32x4& d, bf16x8 ah, bf16x8 al,
                                      bf16x8 bh, bf16x8 bl) {
  d = __builtin_amdgcn_mfma_f32_16x16x32_bf16(ah, bh, d, 0, 0, 0);
  d = __builtin_amdgcn_mfma_f32_16x16x32_bf16(ah, bl, d, 0, 0, 0);
  d = __builtin_amdgcn_mfma_f32_16x16x32_bf16(al, bh, d, 0, 0, 0);
}
// 2-term (B bf16-only)
__device__ __forceinline__ void mfma2(f32x4& d, bf16x8 ah, bf16x8 al, bf16x8 bh) {
  d = __builtin_amdgcn_mfma_f32_16x16x32_bf16(ah, bh, d, 0, 0, 0);
  d = __builtin_amdgcn_mfma_f32_16x16x32_bf16(al, bh, d, 0, 0, 0);
}

__device__ __forceinline__ bf16x8 ldfrag(const unsigned short* p) {
  return *reinterpret_cast<const bf16x8*>(p);
}

// ---------------------------------------------------------------------------
// prep: split x -> Xhi/Xlo; transpose+split W[k][n] -> WT[n][k] hi/lo.
// (unchanged from round 14)
// ---------------------------------------------------------------------------
struct PrepTab {
  const float* src[8];
  unsigned short* hi[8];
  unsigned short* lo[8];
};

__global__ __launch_bounds__(256) void prep_kernel(PrepTab t) {
  const int seg = blockIdx.z;
  const int rows = (seg == 0) ? 768 : 512;
  const int cols = (seg == 5) ? 64 : ((seg == 6) ? 8 : 512);
  const int tx = (seg == 6) ? 2 : ((cols + 31) >> 5);
  const int ty = rows >> 5;
  if ((int)blockIdx.x >= tx || (int)blockIdx.y >= ty) return;
  const int r0 = blockIdx.y * 32, c0 = blockIdx.x * 32;
  const int tid = threadIdx.x;
  const int rl = tid >> 3, c4 = (tid & 7) << 2;
  const float* src = t.src[seg];
  if (seg == 0) {
    float4 v = *(const float4*)(src + (size_t)(r0 + rl) * cols + c0 + c4);
    unsigned short h[4], l[4];
    split1(v.x, h[0], l[0]); split1(v.y, h[1], l[1]);
    split1(v.z, h[2], l[2]); split1(v.w, h[3], l[3]);
    size_t off = (size_t)(r0 + rl) * cols + c0 + c4;
    *(ushort4*)(t.hi[seg] + off) = make_ushort4(h[0], h[1], h[2], h[3]);
    *(ushort4*)(t.lo[seg] + off) = make_ushort4(l[0], l[1], l[2], l[3]);
  } else {
    __shared__ float ts[32][33];
    #pragma unroll
    for (int j = 0; j < 4; ++j) {
      int c = c4 + j;
      ts[rl][c] = (c0 + c < cols) ? src[(size_t)(r0 + rl) * cols + c0 + c] : 0.0f;
    }
    __syncthreads();
    float v0 = ts[c4 + 0][rl], v1 = ts[c4 + 1][rl];
    float v2 = ts[c4 + 2][rl], v3 = ts[c4 + 3][rl];
    unsigned short h[4], l[4];
    split1(v0, h[0], l[0]); split1(v1, h[1], l[1]);
    split1(v2, h[2], l[2]); split1(v3, h[3], l[3]);
    size_t off = (size_t)(c0 + rl) * 512 + r0 + c4;
    *(ushort4*)(t.hi[seg] + off) = make_ushort4(h[0], h[1], h[2], h[3]);
    *(ushort4*)(t.lo[seg] + off) = make_ushort4(l[0], l[1], l[2], l[3]);
  }
}

// ---------------------------------------------------------------------------
// Fused projections via MFMA — LDS chunk-staged (m97-style): 256 threads,
// 64x64 tile, 8 chunks of K=64. Per chunk: batched b128 global->LDS copies
// of the pre-split Xhi/Xlo and WT slabs (latency absorbed once per chunk
// across all waves), then 2 k-iters of pure ds_read_b128 + MFMA.
// Pitch 72 shorts: rows 16B-aligned; lane aliasing is 2-way (free, m136).
// Epilogue routing identical to round 14.
// ---------------------------------------------------------------------------
struct ProjTab {
  const unsigned short* whi[6];
  const unsigned short* wlo[6];
  const float* bias[6];
};

__global__ __launch_bounds__(256) void proj_mfma_kernel(
    const unsigned short* __restrict__ Xhi, const unsigned short* __restrict__ Xlo,
    ProjTab pt,
    unsigned short* __restrict__ Qhi, unsigned short* __restrict__ Qlo,
    unsigned short* __restrict__ Khi, unsigned short* __restrict__ Klo,
    unsigned short* __restrict__ VThi,
    unsigned short* __restrict__ QIhi, unsigned short* __restrict__ QIlo,
    unsigned short* __restrict__ KIhi, unsigned short* __restrict__ KIlo,
    float* __restrict__ WI) {
  __shared__ __align__(16) unsigned short Ah[64][72];
  __shared__ __align__(16) unsigned short Al[64][72];
  __shared__ __align__(16) unsigned short Bh[64][72];
  __shared__ __align__(16) unsigned short Bl[64][72];
  const int bx = blockIdx.x;
  int seg, nt;
  if (bx < 32) { seg = bx >> 3; nt = bx & 7; }
  else         { seg = 4 + (bx - 32); nt = 0; }
  const int m0 = blockIdx.y * 64;
  const int n0 = nt * 64;
  const int tid = threadIdx.x;
  const int lane = tid & 63;
  const int wave = tid >> 6;
  const int mq = (wave >> 1) << 5;        // 0 or 32
  const int nq = (wave & 1) << 5;         // 0 or 32
  const int l15 = lane & 15;
  const int q8 = (lane >> 4) << 3;
  const int q4 = (lane >> 4) << 2;
  const unsigned short* Whi = pt.whi[seg];
  const unsigned short* Wlo = pt.wlo[seg];

  f32x4 acc[2][2] = {};
  for (int cc = 0; cc < 8; ++cc) {
    const int k0 = cc << 6;
    // ---- stage chunk: 64 rows x 64 k of A (x) and B (WT), hi+lo ----
    #pragma unroll
    for (int j = 0; j < 2; ++j) {
      const int flat = tid + (j << 8);        // 0..511
      const int mm = flat >> 3;               // 0..63
      const int kc = (flat & 7) << 3;         // 0,8,..,56
      const size_t ga = (size_t)(m0 + mm) * 512 + k0 + kc;
      const size_t gb = (size_t)(n0 + mm) * 512 + k0 + kc;
      *(bf16x8*)&Ah[mm][kc] = ldfrag(Xhi + ga);
      *(bf16x8*)&Al[mm][kc] = ldfrag(Xlo + ga);
      *(bf16x8*)&Bh[mm][kc] = ldfrag(Whi + gb);
      *(bf16x8*)&Bl[mm][kc] = ldfrag(Wlo + gb);
    }
    __syncthreads();
    // ---- compute: 2 k-iters of 12 MFMA from LDS ----
    #pragma unroll
    for (int ki = 0; ki < 64; ki += 32) {
      const int kk = ki + q8;
      bf16x8 ah0 = *(const bf16x8*)&Ah[mq + l15][kk];
      bf16x8 al0 = *(const bf16x8*)&Al[mq + l15][kk];
      bf16x8 ah1 = *(const bf16x8*)&Ah[mq + 16 + l15][kk];
      bf16x8 al1 = *(const bf16x8*)&Al[mq + 16 + l15][kk];
      bf16x8 bh0 = *(const bf16x8*)&Bh[nq + l15][kk];
      bf16x8 bl0 = *(const bf16x8*)&Bl[nq + l15][kk];
      bf16x8 bh1 = *(const bf16x8*)&Bh[nq + 16 + l15][kk];
      bf16x8 bl1 = *(const bf16x8*)&Bl[nq + 16 + l15][kk];
      mfma3(acc[0][0], ah0, al0, bh0, bl0);
      mfma3(acc[0][1], ah0, al0, bh1, bl1);
      mfma3(acc[1][0], ah1, al1, bh0, bl0);
      mfma3(acc[1][1], ah1, al1, bh1, bl1);
    }
    __syncthreads();
  }

  // ---- epilogue: per-seg routing (identical to round 14) ----
  const float* bias = pt.bias[seg];
  #pragma unroll
  for (int ntt = 0; ntt < 2; ++ntt) {
    const int nloc = n0 + nq + ntt * 16 + l15;
    const float bv = (seg == 5 && nloc >= 8) ? 0.0f : bias[nloc];
    #pragma unroll
    for (int mt = 0; mt < 2; ++mt) {
      #pragma unroll
      for (int r = 0; r < 4; ++r) {
        const int m = m0 + mq + mt * 16 + q4 + r;
        const float v = acc[mt][ntt][r] + bv;
        unsigned short h16, l16;
        if (seg == 0) {
          split1(v, h16, l16);
          Qhi[(size_t)m * 512 + nloc] = h16;
          Qlo[(size_t)m * 512 + nloc] = l16;
        } else if (seg == 1) {
          const int hh = nloc >> 6, dd = nloc & 63;
          split1(v, h16, l16);
          Khi[((size_t)hh * S + m) * 64 + dd] = h16;
          Klo[((size_t)hh * S + m) * 64 + dd] = l16;
        } else if (seg == 2) {
          VThi[((size_t)(nloc >> 6) * 64 + (nloc & 63)) * S + m] = f2bf(v);
        } else if (seg == 3) {
          split1(v, h16, l16);
          QIhi[(size_t)m * 512 + nloc] = h16;
          QIlo[(size_t)m * 512 + nloc] = l16;
        } else if (seg == 4) {
          split1(v, h16, l16);
          KIhi[(size_t)m * 64 + nloc] = h16;
          KIlo[(size_t)m * 64 + nloc] = l16;
        } else {
          if (nloc < 8) WI[(size_t)m * 8 + nloc] = v;
        }
      }
    }
  }
}

// ---------------------------------------------------------------------------
// Indexer via MFMA, internal split over heads, hoisted KI fragments
// (unchanged from round 14).
// ---------------------------------------------------------------------------
__global__ __launch_bounds__(512) void indexer_mfma_kernel(
    const unsigned short* __restrict__ QIhi, const unsigned short* __restrict__ QIlo,
    const unsigned short* __restrict__ KIhi, const unsigned short* __restrict__ KIlo,
    const float* __restrict__ WI, float* __restrict__ ISC) {
  __shared__ float wis[32][8];
  __shared__ float AccL[32][65];
  const int s0 = blockIdx.y * 32, t0 = blockIdx.x * 64;
  const int tid512 = threadIdx.x;
  const int z = tid512 >> 8;
  const int tid = tid512 & 255;
  const int lane = tid & 63;
  const int wave = tid >> 6;
  const int mq = (wave >> 1) << 4;
  const int nqb = (wave & 1) << 5;
  const int l15 = lane & 15;
  const int q8 = (lane >> 4) << 3;
  const int q4 = (lane >> 4) << 2;
  if (tid512 < 256) wis[tid512 >> 3][tid512 & 7] = WI[(size_t)(s0 + (tid512 >> 3)) * 8 + (tid512 & 7)];
  __syncthreads();

  const size_t arow = (size_t)(s0 + mq + l15) * 512;
  const size_t brow0 = (size_t)(t0 + nqb + l15) * 64;
  const size_t brow1 = (size_t)(t0 + nqb + 16 + l15) * 64;

  bf16x8 kfh[2][2], kfl[2][2];
  #pragma unroll
  for (int kk = 0; kk < 2; ++kk) {
    const int kb = kk * 32 + q8;
    kfh[kk][0] = ldfrag(KIhi + brow0 + kb);
    kfl[kk][0] = ldfrag(KIlo + brow0 + kb);
    kfh[kk][1] = ldfrag(KIhi + brow1 + kb);
    kfl[kk][1] = ldfrag(KIlo + brow1 + kb);
  }

  float accI[2][4] = {};
  #pragma unroll
  for (int hh = 0; hh < 4; ++hh) {
    const int h = z * 4 + hh;
    f32x4 d[2] = {};
    #pragma unroll
    for (int kk = 0; kk < 2; ++kk) {
      const int ka = h * 64 + kk * 32 + q8;
      bf16x8 ah = ldfrag(QIhi + arow + ka);
      bf16x8 al = ldfrag(QIlo + arow + ka);
      mfma3(d[0], ah, al, kfh[kk][0], kfl[kk][0]);
      mfma3(d[1], ah, al, kfh[kk][1], kfl[kk][1]);
    }
    #pragma unroll
    for (int r = 0; r < 4; ++r) {
      const float w = wis[mq + q4 + r][h];
      accI[0][r] = fmaf(fmaxf(d[0][r], 0.0f), w, accI[0][r]);
      accI[1][r] = fmaf(fmaxf(d[1][r], 0.0f), w, accI[1][r]);
    }
  }
  if (z == 1) {
    #pragma unroll
    for (int ntt = 0; ntt < 2; ++ntt)
      #pragma unroll
      for (int r = 0; r < 4; ++r)
        AccL[mq + q4 + r][nqb + ntt * 16 + l15] = accI[ntt][r];
  }
  __syncthreads();
  if (z == 0) {
    #pragma unroll
    for (int ntt = 0; ntt < 2; ++ntt)
      #pragma unroll
      for (int r = 0; r < 4; ++r)
        ISC[(size_t)(s0 + mq + q4 + r) * S + t0 + nqb + ntt * 16 + l15] =
            accI[ntt][r] + AccL[mq + q4 + r][nqb + ntt * 16 + l15];
  }
}

// ---------------------------------------------------------------------------
// Top-k via exact radix select; zeroes Sum and ATTacc (unchanged).
// ---------------------------------------------------------------------------
__global__ __launch_bounds__(256) void topk_kernel(
    const float* __restrict__ ISC, unsigned* __restrict__ Mask,
    float* __restrict__ Sum, float* __restrict__ ATTacc) {
  __shared__ unsigned ordv[768];
  __shared__ int hist[256];
  __shared__ int gsum[16];
  __shared__ int sc[256];
  __shared__ unsigned mw[24];
  __shared__ unsigned sh_prefix;
  __shared__ int sh_R;
  const int s = blockIdx.x;
  const int tid = threadIdx.x;
  for (int i = tid; i < 768; i += 256) {
    float f = ISC[s * 768 + i] + 0.0f;
    unsigned u = __float_as_uint(f);
    ordv[i] = (u & 0x80000000u) ? ~u : (u | 0x80000000u);
  }
  {
    const float4 z4 = {0.0f, 0.0f, 0.0f, 0.0f};
    if (tid < 128) *(float4*)(ATTacc + (size_t)s * 512 + tid * 4) = z4;
  }
  if (tid < 24) mw[tid] = 0u;
  if (tid < H) Sum[tid * S + s] = 0.0f;
  if (tid == 0) { sh_prefix = 0u; sh_R = TOPK; }
  __syncthreads();
  for (int pass = 0; pass < 4; ++pass) {
    const int shift = 24 - pass * 8;
    hist[tid] = 0;
    __syncthreads();
    const unsigned pm = (pass == 0) ? 0u : (0xFFFFFFFFu << (shift + 8));
    const unsigned pref = sh_prefix;
    for (int i = tid; i < 768; i += 256) {
      unsigned o = ordv[i];
      if ((o & pm) == pref) atomicAdd(&hist[(o >> shift) & 255], 1);
    }
    __syncthreads();
    if (tid < 16) {
      int t = 0;
      #pragma unroll
      for (int k = 0; k < 16; ++k) t += hist[tid * 16 + k];
      gsum[tid] = t;
    }
    __syncthreads();
    if (tid == 0) {
      int R = sh_R;
      int G = 0;
      int g = 15;
      for (; g > 0; --g) {
        if (G + gsum[g] >= R) break;
        G += gsum[g];
      }
      int b = 15;
      for (; b > 0; --b) {
        int c = hist[g * 16 + b];
        if (G + c >= R) break;
        G += c;
      }
      sh_prefix = sh_prefix | ((unsigned)(g * 16 + b) << shift);
      sh_R = R - G;
    }
    __syncthreads();
  }
  const unsigned thr = sh_prefix;
  const int need_eq = sh_R;
  const int base = tid * 3;
  unsigned o0 = ordv[base], o1 = ordv[base + 1], o2 = ordv[base + 2];
  int c = (o0 == thr) + (o1 == thr) + (o2 == thr);
  sc[tid] = c;
  __syncthreads();
  for (int off = 1; off < 256; off <<= 1) {
    int v = (tid >= off) ? sc[tid - off] : 0;
    __syncthreads();
    sc[tid] += v;
    __syncthreads();
  }
  int rank = sc[tid] - c;
  if (o0 > thr || (o0 == thr && rank < need_eq))
    atomicOr(&mw[base >> 5], 1u << (base & 31));
  if (o0 == thr) ++rank;
  if (o1 > thr || (o1 == thr && rank < need_eq))
    atomicOr(&mw[(base + 1) >> 5], 1u << ((base + 1) & 31));
  if (o1 == thr) ++rank;
  if (o2 > thr || (o2 == thr && rank < need_eq))
    atomicOr(&mw[(base + 2) >> 5], 1u << ((base + 2) & 31));
  __syncthreads();
  if (tid < 24) Mask[s * 24 + tid] = mw[tid];
}

// ---------------------------------------------------------------------------
// Fused masked attention via MFMA. QK 3-term; PV 2-term. Direct atomics
// into ATTacc (unchanged from round 14).
// ---------------------------------------------------------------------------
__global__ __launch_bounds__(256) void sattn_kernel(
    const unsigned short* __restrict__ Qhi, const unsigned short* __restrict__ Qlo,
    const unsigned short* __restrict__ Khi, const unsigned short* __restrict__ Klo,
    const unsigned short* __restrict__ VThi,
    const unsigned* __restrict__ Mask, float* __restrict__ ATTacc,
    float* __restrict__ Sum) {
  __shared__ __align__(16) unsigned short Pshi[32][40];
  __shared__ __align__(16) unsigned short Pslo[32][40];
  __shared__ unsigned msk[32][6];
  __shared__ float rsumf[32];
  const int ks = blockIdx.x;
  const int s0 = blockIdx.y * 32;
  const int h  = blockIdx.z;
  const int tid = threadIdx.x;
  const int lane = tid & 63;
  const int wave = tid >> 6;
  const int l15 = lane & 15;
  const int q8 = (lane >> 4) << 3;
  const int q4 = (lane >> 4) << 2;
  const int mq = (wave >> 1) << 4;
  const int nq = (wave & 1) << 4;
  const int db = (wave & 1) << 5;

  if (tid < 192) msk[tid & 31][tid >> 5] = Mask[(size_t)(s0 + (tid & 31)) * 24 + ks * 6 + (tid >> 5)];
  if (tid < 32) rsumf[tid] = 0.0f;
  __syncthreads();

  const size_t qrow = (size_t)(s0 + mq + l15) * 512 + h * 64;
  bf16x8 qh0 = ldfrag(Qhi + qrow + 0 + q8);
  bf16x8 ql0 = ldfrag(Qlo + qrow + 0 + q8);
  bf16x8 qh1 = ldfrag(Qhi + qrow + 32 + q8);
  bf16x8 ql1 = ldfrag(Qlo + qrow + 32 + q8);

  f32x4 oacc[2] = {};
  for (int ct = 0; ct < 6; ++ct) {
    const int tch = ks * 192 + ct * 32;
    f32x4 d = {0.0f, 0.0f, 0.0f, 0.0f};
    const size_t krow = ((size_t)h * S + tch + nq + l15) * 64;
    {
      bf16x8 bh0 = ldfrag(Khi + krow + 0 + q8);
      bf16x8 bl0 = ldfrag(Klo + krow + 0 + q8);
      bf16x8 bh1 = ldfrag(Khi + krow + 32 + q8);
      bf16x8 bl1 = ldfrag(Klo + krow + 32 + q8);
      mfma3(d, qh0, ql0, bh0, bl0);
      mfma3(d, qh1, ql1, bh1, bl1);
    }
    const int tl = ct * 32 + nq + l15;
    float e[4];
    #pragma unroll
    for (int r = 0; r < 4; ++r) {
      const int srow = mq + q4 + r;
      const unsigned w = msk[srow][tl >> 5];
      e[r] = ((w >> (tl & 31)) & 1u) ? __expf(d[r] * 0.125f) : 0.0f;
      unsigned short h16, l16;
      split1(e[r], h16, l16);
      Pshi[srow][nq + l15] = h16;
      Pslo[srow][nq + l15] = l16;
    }
    float v0 = e[0], v1 = e[1], v2 = e[2], v3 = e[3];
    #pragma unroll
    for (int off = 1; off < 16; off <<= 1) {
      v0 += __shfl_xor(v0, off);
      v1 += __shfl_xor(v1, off);
      v2 += __shfl_xor(v2, off);
      v3 += __shfl_xor(v3, off);
    }
    if (l15 == 0) {
      atomicAdd(&rsumf[mq + q4 + 0], v0);
      atomicAdd(&rsumf[mq + q4 + 1], v1);
      atomicAdd(&rsumf[mq + q4 + 2], v2);
      atomicAdd(&rsumf[mq + q4 + 3], v3);
    }
    __syncthreads();
    bf16x8 pah = *(const bf16x8*)&Pshi[mq + l15][q8];
    bf16x8 pal = *(const bf16x8*)&Pslo[mq + l15][q8];
    #pragma unroll
    for (int dt = 0; dt < 2; ++dt) {
      const size_t vrow = ((size_t)h * 64 + db + dt * 16 + l15) * S + tch;
      bf16x8 vbh = ldfrag(VThi + vrow + q8);
      mfma2(oacc[dt], pah, pal, vbh);
    }
    __syncthreads();
  }
  #pragma unroll
  for (int dt = 0; dt < 2; ++dt) {
    const int dd = db + dt * 16 + l15;
    #pragma unroll
    for (int r = 0; r < 4; ++r) {
      const int s = s0 + mq + q4 + r;
      atomicAdd(&ATTacc[(size_t)s * E + h * DK + dd], oacc[dt][r]);
    }
  }
  if (tid < 32) atomicAdd(&Sum[(size_t)h * S + s0 + tid], rsumf[tid]);
}

// ---------------------------------------------------------------------------
// Output projection via MFMA, 2-term, internal split-K, register prefetch.
// Reads fp32 ATTacc + Sum; normalize + bf16-split in-register (unchanged).
// ---------------------------------------------------------------------------
__global__ __launch_bounds__(512) void out_mfma_kernel(
    const float* __restrict__ ATTacc, const float* __restrict__ Sum,
    const unsigned short* __restrict__ WoThi,
    const float* __restrict__ bo, float* __restrict__ out) {
  __shared__ float AccL[16][65];
  __shared__ float ivs[16][8];
  const int tid512 = threadIdx.x;
  const int wave8 = tid512 >> 6;
  const int z = wave8 >> 2;
  const int wave = wave8 & 3;
  const int lane = tid512 & 63;
  const int m0 = blockIdx.y * 16;
  const int n0 = blockIdx.x * 64 + wave * 16;
  const int l15 = lane & 15;
  const int q8 = (lane >> 4) << 3;
  const int q4 = (lane >> 4) << 2;
  if (tid512 < 128) {
    const int r = tid512 >> 3, hh = tid512 & 7;
    ivs[r][hh] = 1.0f / Sum[(size_t)hh * S + m0 + r];
  }
  __syncthreads();
  const size_t arow = (size_t)(m0 + l15) * 512;
  const size_t brow = (size_t)(n0 + l15) * 512;
  int ko = (z << 8) + q8;
  bf16x8 cah, cal;
  {
    const float inv0 = ivs[l15][(ko >> 6) & 7];
    float4 a = *(const float4*)(ATTacc + arow + ko);
    float4 b = *(const float4*)(ATTacc + arow + ko + 4);
    float v[8] = {a.x, a.y, a.z, a.w, b.x, b.y, b.z, b.w};
    #pragma unroll
    for (int i = 0; i < 8; ++i) {
      unsigned short hh, ll;
      split1(v[i] * inv0, hh, ll);
      cah[i] = (short)hh; cal[i] = (short)ll;
    }
  }
  bf16x8 cbh = ldfrag(WoThi + brow + ko);
  f32x4 acc = {};
  #pragma unroll
  for (int it = 0; it < 8; ++it) {
    const int kn = ko + 32;
    float4 na = *(const float4*)(ATTacc + arow + kn);       // benign overread
    float4 nb = *(const float4*)(ATTacc + arow + kn + 4);   //  on last iter
    bf16x8 nbh = ldfrag(WoThi + brow + kn);
    mfma2(acc, cah, cal, cbh);
    const float invn = ivs[l15][(kn >> 6) & 7];
    float v[8] = {na.x, na.y, na.z, na.w, nb.x, nb.y, nb.z, nb.w};
    #pragma unroll
    for (int i = 0; i < 8; ++i) {
      unsigned short hh, ll;
      split1(v[i] * invn, hh, ll);
      cah[i] = (short)hh; cal[i] = (short)ll;
    }
    cbh = nbh;
    ko = kn;
  }
  if (z == 1) {
    #pragma unroll
    for (int r = 0; r < 4; ++r)
      AccL[q4 + r][wave * 16 + l15] = acc[r];
  }
  __syncthreads();
  if (z == 0) {
    const int n = n0 + l15;
    const float bv = bo[n];
    #pragma unroll
    for (int r = 0; r < 4; ++r)
      out[(size_t)(m0 + q4 + r) * 512 + n] =
          acc[r] + AccL[q4 + r][wave * 16 + l15] + bv;
  }
}

// ---------------------------------------------------------------------------
// Launch
// ---------------------------------------------------------------------------
extern "C" void kernel_launch(void* const* d_in, const int* in_sizes, int n_in,
                              void* d_out, int out_size, void* d_ws, size_t ws_size,
                              hipStream_t stream) {
  const float* x    = (const float*)d_in[0];
  const float* Wq   = (const float*)d_in[1];
  const float* bq   = (const float*)d_in[2];
  const float* Wk   = (const float*)d_in[3];
  const float* bk   = (const float*)d_in[4];
  const float* Wv   = (const float*)d_in[5];
  const float* bv   = (const float*)d_in[6];
  const float* Wo   = (const float*)d_in[7];
  const float* bo   = (const float*)d_in[8];
  const float* iqW  = (const float*)d_in[9];
  const float* iqb  = (const float*)d_in[10];
  const float* ikW  = (const float*)d_in[11];
  const float* ikb  = (const float*)d_in[12];
  const float* wpW  = (const float*)d_in[13];
  const float* wpb  = (const float*)d_in[14];

  float* ws = (float*)d_ws;
  float* WI   = ws;                         // S*H fp32
  float* ISC  = WI + S * H;                 // S*S fp32
  unsigned* Mask = (unsigned*)(ISC + S * S);  // S*24
  float* Sum  = (float*)(Mask + S * 24);    // H*S
  float* ATTacc = Sum + H * S;              // S*E fp32 (atomic accumulator)
  unsigned short* u = (unsigned short*)(ATTacc + S * E);
  unsigned short* Xhi  = u;             u += S * E;
  unsigned short* Xlo  = u;             u += S * E;
  unsigned short* Qhi  = u;             u += S * E;
  unsigned short* Qlo  = u;             u += S * E;
  unsigned short* Khi  = u;             u += S * E;
  unsigned short* Klo  = u;             u += S * E;
  unsigned short* VThi = u;             u += S * E;
  unsigned short* QIhi = u;             u += S * E;
  unsigned short* QIlo = u;             u += S * E;
  unsigned short* KIhi = u;             u += S * DK;
  unsigned short* KIlo = u;             u += S * DK;
  unsigned short* WTq_hi = u;           u += E * E;
  unsigned short* WTk_hi = u;           u += E * E;
  unsigned short* WTv_hi = u;           u += E * E;
  unsigned short* WTiq_hi = u;          u += E * E;
  unsigned short* WTik_hi = u;          u += 64 * E;
  unsigned short* WTwp_hi = u;          u += 64 * E;
  unsigned short* WTo_hi = u;           u += E * E;
  unsigned short* WTq_lo = u;           u += E * E;
  unsigned short* WTk_lo = u;           u += E * E;
  unsigned short* WTv_lo = u;           u += E * E;
  unsigned short* WTiq_lo = u;          u += E * E;
  unsigned short* WTik_lo = u;          u += 64 * E;
  unsigned short* WTwp_lo = u;          u += 64 * E;
  unsigned short* WTo_lo = u;           u += E * E;

  PrepTab prep;
  prep.src[0] = x;    prep.hi[0] = Xhi;     prep.lo[0] = Xlo;
  prep.src[1] = Wq;   prep.hi[1] = WTq_hi;  prep.lo[1] = WTq_lo;
  prep.src[2] = Wk;   prep.hi[2] = WTk_hi;  prep.lo[2] = WTk_lo;
  prep.src[3] = Wv;   prep.hi[3] = WTv_hi;  prep.lo[3] = WTv_lo;
  prep.src[4] = iqW;  prep.hi[4] = WTiq_hi; prep.lo[4] = WTiq_lo;
  prep.src[5] = ikW;  prep.hi[5] = WTik_hi; prep.lo[5] = WTik_lo;
  prep.src[6] = wpW;  prep.hi[6] = WTwp_hi; prep.lo[6] = WTwp_lo;
  prep.src[7] = Wo;   prep.hi[7] = WTo_hi;  prep.lo[7] = WTo_lo;

  ProjTab pt;
  pt.whi[0] = WTq_hi;  pt.wlo[0] = WTq_lo;  pt.bias[0] = bq;
  pt.whi[1] = WTk_hi;  pt.wlo[1] = WTk_lo;  pt.bias[1] = bk;
  pt.whi[2] = WTv_hi;  pt.wlo[2] = WTv_lo;  pt.bias[2] = bv;
  pt.whi[3] = WTiq_hi; pt.wlo[3] = WTiq_lo; pt.bias[3] = iqb;
  pt.whi[4] = WTik_hi; pt.wlo[4] = WTik_lo; pt.bias[4] = ikb;
  pt.whi[5] = WTwp_hi; pt.wlo[5] = WTwp_lo; pt.bias[5] = wpb;

  // 1) split x + transpose/split all weight matrices
  prep_kernel<<<dim3(16, 24, 8), dim3(256), 0, stream>>>(prep);
  // 2) projections via MFMA, LDS chunk-staged: 34 x 12 = 408 blocks x 4 waves
  proj_mfma_kernel<<<dim3(34, S / 64), dim3(256), 0, stream>>>(
      Xhi, Xlo, pt, Qhi, Qlo, Khi, Klo, VThi, QIhi, QIlo, KIhi, KIlo, WI);
  // 3) indexer via MFMA (split-h, hoisted KI fragments)
  indexer_mfma_kernel<<<dim3(S / 64, S / 32), dim3(512), 0, stream>>>(
      QIhi, QIlo, KIhi, KIlo, WI, ISC);
  // 4) top-k per row (radix select; zeroes Sum and ATTacc)
  topk_kernel<<<dim3(S), dim3(256), 0, stream>>>(ISC, Mask, Sum, ATTacc);
  // 5) fused masked attention via MFMA -> fp32 atomics into ATTacc
  sattn_kernel<<<dim3(4, S / 32, H), dim3(256), 0, stream>>>(
      Qhi, Qlo, Khi, Klo, VThi, Mask, ATTacc, Sum);
  // 6) output projection (reads ATTacc+Sum; normalize+split in-register)
  out_mfma_kernel<<<dim3(8, 48), dim3(512), 0, stream>>>(
      ATTacc, Sum, WTo_hi, bo, (float*)d_out);
}

// Round 16
// 151.231 us; speedup vs baseline: 1.2357x; 1.0393x over previous
//
#include <hip/hip_runtime.h>
#include <hip/hip_bf16.h>
#include <math.h>

// Problem constants
#define S 768
#define E 512
#define H 8
#define DK 64
#define TOPK 384

typedef short bf16x8 __attribute__((ext_vector_type(8)));
typedef float f32x4 __attribute__((ext_vector_type(4)));

// ---------------------------------------------------------------------------
// fp32 <-> bf16 split helpers (round-to-nearest-even)
// ---------------------------------------------------------------------------
__device__ __forceinline__ unsigned short f2bf(float x) {
  unsigned u = __float_as_uint(x);
  unsigned r = u + 0x7FFFu + ((u >> 16) & 1u);
  return (unsigned short)(r >> 16);
}
__device__ __forceinline__ float bf2f(unsigned short h) {
  return __uint_as_float(((unsigned)h) << 16);
}
__device__ __forceinline__ void split1(float x, unsigned short& h, unsigned short& l) {
  h = f2bf(x);
  l = f2bf(x - bf2f(h));
}

// 3-term fp32-accurate bf16 MFMA
__device__ __forceinline__ void mfma3(f32x4& d, bf16x8 ah, bf16x8 al,
                                      bf16x8 bh, bf16x8 bl) {
  d = __builtin_amdgcn_mfma_f32_16x16x32_bf16(ah, bh, d, 0, 0, 0);
  d = __builtin_amdgcn_mfma_f32_16x16x32_bf16(ah, bl, d, 0, 0, 0);
  d = __builtin_amdgcn_mfma_f32_16x16x32_bf16(al, bh, d, 0, 0, 0);
}
// 2-term (B bf16-only)
__device__ __forceinline__ void mfma2(f32x4& d, bf16x8 ah, bf16x8 al, bf16x8 bh) {
  d = __builtin_amdgcn_mfma_f32_16x16x32_bf16(ah, bh, d, 0, 0, 0);
  d = __builtin_amdgcn_mfma_f32_16x16x32_bf16(al, bh, d, 0, 0, 0);
}

__device__ __forceinline__ bf16x8 ldfrag(const unsigned short* p) {
  return *reinterpret_cast<const bf16x8*>(p);
}

// ---------------------------------------------------------------------------
// prep (unchanged)
// ---------------------------------------------------------------------------
struct PrepTab {
  const float* src[8];
  unsigned short* hi[8];
  unsigned short* lo[8];
};

__global__ __launch_bounds__(256) void prep_kernel(PrepTab t) {
  const int seg = blockIdx.z;
  const int rows = (seg == 0) ? 768 : 512;
  const int cols = (seg == 5) ? 64 : ((seg == 6) ? 8 : 512);
  const int tx = (seg == 6) ? 2 : ((cols + 31) >> 5);
  const int ty = rows >> 5;
  if ((int)blockIdx.x >= tx || (int)blockIdx.y >= ty) return;
  const int r0 = blockIdx.y * 32, c0 = blockIdx.x * 32;
  const int tid = threadIdx.x;
  const int rl = tid >> 3, c4 = (tid & 7) << 2;
  const float* src = t.src[seg];
  if (seg == 0) {
    float4 v = *(const float4*)(src + (size_t)(r0 + rl) * cols + c0 + c4);
    unsigned short h[4], l[4];
    split1(v.x, h[0], l[0]); split1(v.y, h[1], l[1]);
    split1(v.z, h[2], l[2]); split1(v.w, h[3], l[3]);
    size_t off = (size_t)(r0 + rl) * cols + c0 + c4;
    *(ushort4*)(t.hi[seg] + off) = make_ushort4(h[0], h[1], h[2], h[3]);
    *(ushort4*)(t.lo[seg] + off) = make_ushort4(l[0], l[1], l[2], l[3]);
  } else {
    __shared__ float ts[32][33];
    #pragma unroll
    for (int j = 0; j < 4; ++j) {
      int c = c4 + j;
      ts[rl][c] = (c0 + c < cols) ? src[(size_t)(r0 + rl) * cols + c0 + c] : 0.0f;
    }
    __syncthreads();
    float v0 = ts[c4 + 0][rl], v1 = ts[c4 + 1][rl];
    float v2 = ts[c4 + 2][rl], v3 = ts[c4 + 3][rl];
    unsigned short h[4], l[4];
    split1(v0, h[0], l[0]); split1(v1, h[1], l[1]);
    split1(v2, h[2], l[2]); split1(v3, h[3], l[3]);
    size_t off = (size_t)(c0 + rl) * 512 + r0 + c4;
    *(ushort4*)(t.hi[seg] + off) = make_ushort4(h[0], h[1], h[2], h[3]);
    *(ushort4*)(t.lo[seg] + off) = make_ushort4(l[0], l[1], l[2], l[3]);
  }
}

// ---------------------------------------------------------------------------
// Fused projections via MFMA — LDS chunk-staged (unchanged from round 15).
// ---------------------------------------------------------------------------
struct ProjTab {
  const unsigned short* whi[6];
  const unsigned short* wlo[6];
  const float* bias[6];
};

__global__ __launch_bounds__(256) void proj_mfma_kernel(
    const unsigned short* __restrict__ Xhi, const unsigned short* __restrict__ Xlo,
    ProjTab pt,
    unsigned short* __restrict__ Qhi, unsigned short* __restrict__ Qlo,
    unsigned short* __restrict__ Khi, unsigned short* __restrict__ Klo,
    unsigned short* __restrict__ VThi,
    unsigned short* __restrict__ QIhi, unsigned short* __restrict__ QIlo,
    unsigned short* __restrict__ KIhi, unsigned short* __restrict__ KIlo,
    float* __restrict__ WI) {
  __shared__ __align__(16) unsigned short Ah[64][72];
  __shared__ __align__(16) unsigned short Al[64][72];
  __shared__ __align__(16) unsigned short Bh[64][72];
  __shared__ __align__(16) unsigned short Bl[64][72];
  const int bx = blockIdx.x;
  int seg, nt;
  if (bx < 32) { seg = bx >> 3; nt = bx & 7; }
  else         { seg = 4 + (bx - 32); nt = 0; }
  const int m0 = blockIdx.y * 64;
  const int n0 = nt * 64;
  const int tid = threadIdx.x;
  const int lane = tid & 63;
  const int wave = tid >> 6;
  const int mq = (wave >> 1) << 5;
  const int nq = (wave & 1) << 5;
  const int l15 = lane & 15;
  const int q8 = (lane >> 4) << 3;
  const int q4 = (lane >> 4) << 2;
  const unsigned short* Whi = pt.whi[seg];
  const unsigned short* Wlo = pt.wlo[seg];

  f32x4 acc[2][2] = {};
  for (int cc = 0; cc < 8; ++cc) {
    const int k0 = cc << 6;
    #pragma unroll
    for (int j = 0; j < 2; ++j) {
      const int flat = tid + (j << 8);
      const int mm = flat >> 3;
      const int kc = (flat & 7) << 3;
      const size_t ga = (size_t)(m0 + mm) * 512 + k0 + kc;
      const size_t gb = (size_t)(n0 + mm) * 512 + k0 + kc;
      *(bf16x8*)&Ah[mm][kc] = ldfrag(Xhi + ga);
      *(bf16x8*)&Al[mm][kc] = ldfrag(Xlo + ga);
      *(bf16x8*)&Bh[mm][kc] = ldfrag(Whi + gb);
      *(bf16x8*)&Bl[mm][kc] = ldfrag(Wlo + gb);
    }
    __syncthreads();
    #pragma unroll
    for (int ki = 0; ki < 64; ki += 32) {
      const int kk = ki + q8;
      bf16x8 ah0 = *(const bf16x8*)&Ah[mq + l15][kk];
      bf16x8 al0 = *(const bf16x8*)&Al[mq + l15][kk];
      bf16x8 ah1 = *(const bf16x8*)&Ah[mq + 16 + l15][kk];
      bf16x8 al1 = *(const bf16x8*)&Al[mq + 16 + l15][kk];
      bf16x8 bh0 = *(const bf16x8*)&Bh[nq + l15][kk];
      bf16x8 bl0 = *(const bf16x8*)&Bl[nq + l15][kk];
      bf16x8 bh1 = *(const bf16x8*)&Bh[nq + 16 + l15][kk];
      bf16x8 bl1 = *(const bf16x8*)&Bl[nq + 16 + l15][kk];
      mfma3(acc[0][0], ah0, al0, bh0, bl0);
      mfma3(acc[0][1], ah0, al0, bh1, bl1);
      mfma3(acc[1][0], ah1, al1, bh0, bl0);
      mfma3(acc[1][1], ah1, al1, bh1, bl1);
    }
    __syncthreads();
  }

  const float* bias = pt.bias[seg];
  #pragma unroll
  for (int ntt = 0; ntt < 2; ++ntt) {
    const int nloc = n0 + nq + ntt * 16 + l15;
    const float bv = (seg == 5 && nloc >= 8) ? 0.0f : bias[nloc];
    #pragma unroll
    for (int mt = 0; mt < 2; ++mt) {
      #pragma unroll
      for (int r = 0; r < 4; ++r) {
        const int m = m0 + mq + mt * 16 + q4 + r;
        const float v = acc[mt][ntt][r] + bv;
        unsigned short h16, l16;
        if (seg == 0) {
          split1(v, h16, l16);
          Qhi[(size_t)m * 512 + nloc] = h16;
          Qlo[(size_t)m * 512 + nloc] = l16;
        } else if (seg == 1) {
          const int hh = nloc >> 6, dd = nloc & 63;
          split1(v, h16, l16);
          Khi[((size_t)hh * S + m) * 64 + dd] = h16;
          Klo[((size_t)hh * S + m) * 64 + dd] = l16;
        } else if (seg == 2) {
          VThi[((size_t)(nloc >> 6) * 64 + (nloc & 63)) * S + m] = f2bf(v);
        } else if (seg == 3) {
          split1(v, h16, l16);
          QIhi[(size_t)m * 512 + nloc] = h16;
          QIlo[(size_t)m * 512 + nloc] = l16;
        } else if (seg == 4) {
          split1(v, h16, l16);
          KIhi[(size_t)m * 64 + nloc] = h16;
          KIlo[(size_t)m * 64 + nloc] = l16;
        } else {
          if (nloc < 8) WI[(size_t)m * 8 + nloc] = v;
        }
      }
    }
  }
}

// ---------------------------------------------------------------------------
// Indexer via MFMA — LDS-staged QI per head-pair (32s x 128k hi+lo),
// KI hoisted in registers. 256 threads, 4 waves (2x2 quadrants of the
// 32x64 tile). Head-order summation is sequential (relu-zero rows stay
// exactly 0.0; tie-gap ~4e-3 >> 1e-7 perturbation).
// ---------------------------------------------------------------------------
__global__ __launch_bounds__(256) void indexer_mfma_kernel(
    const unsigned short* __restrict__ QIhi, const unsigned short* __restrict__ QIlo,
    const unsigned short* __restrict__ KIhi, const unsigned short* __restrict__ KIlo,
    const float* __restrict__ WI, float* __restrict__ ISC) {
  __shared__ __align__(16) unsigned short Qh[32][136];
  __shared__ __align__(16) unsigned short Ql[32][136];
  __shared__ float wis[32][8];
  const int s0 = blockIdx.y * 32, t0 = blockIdx.x * 64;
  const int tid = threadIdx.x;
  const int lane = tid & 63;
  const int wave = tid >> 6;
  const int mq = (wave >> 1) << 4;   // 0 or 16
  const int nqb = (wave & 1) << 5;   // 0 or 32
  const int l15 = lane & 15;
  const int q8 = (lane >> 4) << 3;
  const int q4 = (lane >> 4) << 2;
  wis[tid >> 3][tid & 7] = WI[(size_t)(s0 + (tid >> 3)) * 8 + (tid & 7)];

  // hoisted head-invariant KI fragments
  const size_t brow0 = (size_t)(t0 + nqb + l15) * 64;
  const size_t brow1 = (size_t)(t0 + nqb + 16 + l15) * 64;
  bf16x8 kfh[2][2], kfl[2][2];
  #pragma unroll
  for (int kk = 0; kk < 2; ++kk) {
    const int kb = kk * 32 + q8;
    kfh[kk][0] = ldfrag(KIhi + brow0 + kb);
    kfl[kk][0] = ldfrag(KIlo + brow0 + kb);
    kfh[kk][1] = ldfrag(KIhi + brow1 + kb);
    kfl[kk][1] = ldfrag(KIlo + brow1 + kb);
  }

  const int smm = tid >> 3;          // staging row 0..31
  const int skc = (tid & 7) << 4;    // staging col base 0..112
  float accI[2][4] = {};
  for (int hp = 0; hp < 4; ++hp) {
    __syncthreads();   // prev compute done reading Qh/Ql (also covers wis)
    {
      const size_t g = (size_t)(s0 + smm) * 512 + hp * 128 + skc;
      *(bf16x8*)&Qh[smm][skc]     = ldfrag(QIhi + g);
      *(bf16x8*)&Qh[smm][skc + 8] = ldfrag(QIhi + g + 8);
      *(bf16x8*)&Ql[smm][skc]     = ldfrag(QIlo + g);
      *(bf16x8*)&Ql[smm][skc + 8] = ldfrag(QIlo + g + 8);
    }
    __syncthreads();
    #pragma unroll
    for (int hh = 0; hh < 2; ++hh) {
      const int h = hp * 2 + hh;
      f32x4 d[2] = {};
      #pragma unroll
      for (int kk = 0; kk < 2; ++kk) {
        const int ka = hh * 64 + kk * 32 + q8;
        bf16x8 ah = *(const bf16x8*)&Qh[mq + l15][ka];
        bf16x8 al = *(const bf16x8*)&Ql[mq + l15][ka];
        mfma3(d[0], ah, al, kfh[kk][0], kfl[kk][0]);
        mfma3(d[1], ah, al, kfh[kk][1], kfl[kk][1]);
      }
      #pragma unroll
      for (int r = 0; r < 4; ++r) {
        const float w = wis[mq + q4 + r][h];
        accI[0][r] = fmaf(fmaxf(d[0][r], 0.0f), w, accI[0][r]);
        accI[1][r] = fmaf(fmaxf(d[1][r], 0.0f), w, accI[1][r]);
      }
    }
  }
  #pragma unroll
  for (int ntt = 0; ntt < 2; ++ntt)
    #pragma unroll
    for (int r = 0; r < 4; ++r)
      ISC[(size_t)(s0 + mq + q4 + r) * S + t0 + nqb + ntt * 16 + l15] = accI[ntt][r];
}

// ---------------------------------------------------------------------------
// Top-k via exact radix select; zeroes Sum and ATTacc (unchanged).
// ---------------------------------------------------------------------------
__global__ __launch_bounds__(256) void topk_kernel(
    const float* __restrict__ ISC, unsigned* __restrict__ Mask,
    float* __restrict__ Sum, float* __restrict__ ATTacc) {
  __shared__ unsigned ordv[768];
  __shared__ int hist[256];
  __shared__ int gsum[16];
  __shared__ int sc[256];
  __shared__ unsigned mw[24];
  __shared__ unsigned sh_prefix;
  __shared__ int sh_R;
  const int s = blockIdx.x;
  const int tid = threadIdx.x;
  for (int i = tid; i < 768; i += 256) {
    float f = ISC[s * 768 + i] + 0.0f;
    unsigned u = __float_as_uint(f);
    ordv[i] = (u & 0x80000000u) ? ~u : (u | 0x80000000u);
  }
  {
    const float4 z4 = {0.0f, 0.0f, 0.0f, 0.0f};
    if (tid < 128) *(float4*)(ATTacc + (size_t)s * 512 + tid * 4) = z4;
  }
  if (tid < 24) mw[tid] = 0u;
  if (tid < H) Sum[tid * S + s] = 0.0f;
  if (tid == 0) { sh_prefix = 0u; sh_R = TOPK; }
  __syncthreads();
  for (int pass = 0; pass < 4; ++pass) {
    const int shift = 24 - pass * 8;
    hist[tid] = 0;
    __syncthreads();
    const unsigned pm = (pass == 0) ? 0u : (0xFFFFFFFFu << (shift + 8));
    const unsigned pref = sh_prefix;
    for (int i = tid; i < 768; i += 256) {
      unsigned o = ordv[i];
      if ((o & pm) == pref) atomicAdd(&hist[(o >> shift) & 255], 1);
    }
    __syncthreads();
    if (tid < 16) {
      int t = 0;
      #pragma unroll
      for (int k = 0; k < 16; ++k) t += hist[tid * 16 + k];
      gsum[tid] = t;
    }
    __syncthreads();
    if (tid == 0) {
      int R = sh_R;
      int G = 0;
      int g = 15;
      for (; g > 0; --g) {
        if (G + gsum[g] >= R) break;
        G += gsum[g];
      }
      int b = 15;
      for (; b > 0; --b) {
        int c = hist[g * 16 + b];
        if (G + c >= R) break;
        G += c;
      }
      sh_prefix = sh_prefix | ((unsigned)(g * 16 + b) << shift);
      sh_R = R - G;
    }
    __syncthreads();
  }
  const unsigned thr = sh_prefix;
  const int need_eq = sh_R;
  const int base = tid * 3;
  unsigned o0 = ordv[base], o1 = ordv[base + 1], o2 = ordv[base + 2];
  int c = (o0 == thr) + (o1 == thr) + (o2 == thr);
  sc[tid] = c;
  __syncthreads();
  for (int off = 1; off < 256; off <<= 1) {
    int v = (tid >= off) ? sc[tid - off] : 0;
    __syncthreads();
    sc[tid] += v;
    __syncthreads();
  }
  int rank = sc[tid] - c;
  if (o0 > thr || (o0 == thr && rank < need_eq))
    atomicOr(&mw[base >> 5], 1u << (base & 31));
  if (o0 == thr) ++rank;
  if (o1 > thr || (o1 == thr && rank < need_eq))
    atomicOr(&mw[(base + 1) >> 5], 1u << ((base + 1) & 31));
  if (o1 == thr) ++rank;
  if (o2 > thr || (o2 == thr && rank < need_eq))
    atomicOr(&mw[(base + 2) >> 5], 1u << ((base + 2) & 31));
  __syncthreads();
  if (tid < 24) Mask[s * 24 + tid] = mw[tid];
}

// ---------------------------------------------------------------------------
// Fused masked attention via MFMA — LDS-staged K/V chunks, s-tile 64,
// 512 threads (8 waves: mq in {0,16,32,48}, nq/db from wave&1).
// Per 32-t chunk: threads 0..255 stage Khi+Klo (32t x 64d), threads
// 256..511 stage VThi (64d x 32t); QK 3-term, exp+mask, PV 2-term, all
// operand reads from LDS. Direct fp32 atomics into ATTacc.
// ---------------------------------------------------------------------------
__global__ __launch_bounds__(512) void sattn_kernel(
    const unsigned short* __restrict__ Qhi, const unsigned short* __restrict__ Qlo,
    const unsigned short* __restrict__ Khi, const unsigned short* __restrict__ Klo,
    const unsigned short* __restrict__ VThi,
    const unsigned* __restrict__ Mask, float* __restrict__ ATTacc,
    float* __restrict__ Sum) {
  __shared__ __align__(16) unsigned short Pshi[64][40];
  __shared__ __align__(16) unsigned short Pslo[64][40];
  __shared__ __align__(16) unsigned short Ksh[32][72];
  __shared__ __align__(16) unsigned short Ksl[32][72];
  __shared__ __align__(16) unsigned short Vsh[64][40];
  __shared__ unsigned msk[64][6];
  __shared__ float rsumf[64];
  const int ks = blockIdx.x;
  const int s0 = blockIdx.y * 64;
  const int h  = blockIdx.z;
  const int tid = threadIdx.x;
  const int lane = tid & 63;
  const int wave = tid >> 6;          // 0..7
  const int l15 = lane & 15;
  const int q8 = (lane >> 4) << 3;
  const int q4 = (lane >> 4) << 2;
  const int mq = (wave >> 1) << 4;    // 0,16,32,48
  const int nq = (wave & 1) << 4;     // 0 or 16 (t-half)
  const int db = (wave & 1) << 5;     // 0 or 32 (d-half)

  if (tid < 384) msk[tid & 63][tid >> 6] =
      Mask[(size_t)(s0 + (tid & 63)) * 24 + ks * 6 + (tid >> 6)];
  if (tid < 64) rsumf[tid] = 0.0f;

  const size_t qrow = (size_t)(s0 + mq + l15) * 512 + h * 64;
  bf16x8 qh0 = ldfrag(Qhi + qrow + 0 + q8);
  bf16x8 ql0 = ldfrag(Qlo + qrow + 0 + q8);
  bf16x8 qh1 = ldfrag(Qhi + qrow + 32 + q8);
  bf16x8 ql1 = ldfrag(Qlo + qrow + 32 + q8);

  const int t2 = tid & 255;
  f32x4 oacc[2] = {};
  for (int ct = 0; ct < 6; ++ct) {
    const int tch = ks * 192 + ct * 32;
    __syncthreads();   // prev PV done reading Vsh / first-iter msk ready
    if (tid < 256) {
      const int tr = t2 >> 3;          // 0..31
      const int kc = (t2 & 7) << 3;    // 0..56
      const size_t gk = ((size_t)h * S + tch + tr) * 64 + kc;
      *(bf16x8*)&Ksh[tr][kc] = ldfrag(Khi + gk);
      *(bf16x8*)&Ksl[tr][kc] = ldfrag(Klo + gk);
    } else {
      const int vr = t2 >> 2;          // 0..63
      const int tc = (t2 & 3) << 3;    // 0..24
      *(bf16x8*)&Vsh[vr][tc] =
          ldfrag(VThi + ((size_t)h * 64 + vr) * S + tch + tc);
    }
    __syncthreads();
    // ---- QK from LDS ----
    f32x4 d = {0.0f, 0.0f, 0.0f, 0.0f};
    {
      bf16x8 bh0 = *(const bf16x8*)&Ksh[nq + l15][q8];
      bf16x8 bl0 = *(const bf16x8*)&Ksl[nq + l15][q8];
      bf16x8 bh1 = *(const bf16x8*)&Ksh[nq + l15][32 + q8];
      bf16x8 bl1 = *(const bf16x8*)&Ksl[nq + l15][32 + q8];
      mfma3(d, qh0, ql0, bh0, bl0);
      mfma3(d, qh1, ql1, bh1, bl1);
    }
    const int tl = ct * 32 + nq + l15;
    float e[4];
    #pragma unroll
    for (int r = 0; r < 4; ++r) {
      const int srow = mq + q4 + r;
      const unsigned w = msk[srow][tl >> 5];
      e[r] = ((w >> (tl & 31)) & 1u) ? __expf(d[r] * 0.125f) : 0.0f;
      unsigned short h16, l16;
      split1(e[r], h16, l16);
      Pshi[srow][nq + l15] = h16;
      Pslo[srow][nq + l15] = l16;
    }
    float v0 = e[0], v1 = e[1], v2 = e[2], v3 = e[3];
    #pragma unroll
    for (int off = 1; off < 16; off <<= 1) {
      v0 += __shfl_xor(v0, off);
      v1 += __shfl_xor(v1, off);
      v2 += __shfl_xor(v2, off);
      v3 += __shfl_xor(v3, off);
    }
    if (l15 == 0) {
      atomicAdd(&rsumf[mq + q4 + 0], v0);
      atomicAdd(&rsumf[mq + q4 + 1], v1);
      atomicAdd(&rsumf[mq + q4 + 2], v2);
      atomicAdd(&rsumf[mq + q4 + 3], v3);
    }
    __syncthreads();
    // ---- PV from LDS ----
    bf16x8 pah = *(const bf16x8*)&Pshi[mq + l15][q8];
    bf16x8 pal = *(const bf16x8*)&Pslo[mq + l15][q8];
    #pragma unroll
    for (int dt = 0; dt < 2; ++dt) {
      bf16x8 vbh = *(const bf16x8*)&Vsh[db + dt * 16 + l15][q8];
      mfma2(oacc[dt], pah, pal, vbh);
    }
  }
  #pragma unroll
  for (int dt = 0; dt < 2; ++dt) {
    const int dd = db + dt * 16 + l15;
    #pragma unroll
    for (int r = 0; r < 4; ++r) {
      const int s = s0 + mq + q4 + r;
      atomicAdd(&ATTacc[(size_t)s * E + h * DK + dd], oacc[dt][r]);
    }
  }
  __syncthreads();
  if (tid < 64) atomicAdd(&Sum[(size_t)h * S + s0 + tid], rsumf[tid]);
}

// ---------------------------------------------------------------------------
// Output projection via MFMA (unchanged from round 15).
// ---------------------------------------------------------------------------
__global__ __launch_bounds__(512) void out_mfma_kernel(
    const float* __restrict__ ATTacc, const float* __restrict__ Sum,
    const unsigned short* __restrict__ WoThi,
    const float* __restrict__ bo, float* __restrict__ out) {
  __shared__ float AccL[16][65];
  __shared__ float ivs[16][8];
  const int tid512 = threadIdx.x;
  const int wave8 = tid512 >> 6;
  const int z = wave8 >> 2;
  const int wave = wave8 & 3;
  const int lane = tid512 & 63;
  const int m0 = blockIdx.y * 16;
  const int n0 = blockIdx.x * 64 + wave * 16;
  const int l15 = lane & 15;
  const int q8 = (lane >> 4) << 3;
  const int q4 = (lane >> 4) << 2;
  if (tid512 < 128) {
    const int r = tid512 >> 3, hh = tid512 & 7;
    ivs[r][hh] = 1.0f / Sum[(size_t)hh * S + m0 + r];
  }
  __syncthreads();
  const size_t arow = (size_t)(m0 + l15) * 512;
  const size_t brow = (size_t)(n0 + l15) * 512;
  int ko = (z << 8) + q8;
  bf16x8 cah, cal;
  {
    const float inv0 = ivs[l15][(ko >> 6) & 7];
    float4 a = *(const float4*)(ATTacc + arow + ko);
    float4 b = *(const float4*)(ATTacc + arow + ko + 4);
    float v[8] = {a.x, a.y, a.z, a.w, b.x, b.y, b.z, b.w};
    #pragma unroll
    for (int i = 0; i < 8; ++i) {
      unsigned short hh, ll;
      split1(v[i] * inv0, hh, ll);
      cah[i] = (short)hh; cal[i] = (short)ll;
    }
  }
  bf16x8 cbh = ldfrag(WoThi + brow + ko);
  f32x4 acc = {};
  #pragma unroll
  for (int it = 0; it < 8; ++it) {
    const int kn = ko + 32;
    float4 na = *(const float4*)(ATTacc + arow + kn);
    float4 nb = *(const float4*)(ATTacc + arow + kn + 4);
    bf16x8 nbh = ldfrag(WoThi + brow + kn);
    mfma2(acc, cah, cal, cbh);
    const float invn = ivs[l15][(kn >> 6) & 7];
    float v[8] = {na.x, na.y, na.z, na.w, nb.x, nb.y, nb.z, nb.w};
    #pragma unroll
    for (int i = 0; i < 8; ++i) {
      unsigned short hh, ll;
      split1(v[i] * invn, hh, ll);
      cah[i] = (short)hh; cal[i] = (short)ll;
    }
    cbh = nbh;
    ko = kn;
  }
  if (z == 1) {
    #pragma unroll
    for (int r = 0; r < 4; ++r)
      AccL[q4 + r][wave * 16 + l15] = acc[r];
  }
  __syncthreads();
  if (z == 0) {
    const int n = n0 + l15;
    const float bv = bo[n];
    #pragma unroll
    for (int r = 0; r < 4; ++r)
      out[(size_t)(m0 + q4 + r) * 512 + n] =
          acc[r] + AccL[q4 + r][wave * 16 + l15] + bv;
  }
}

// ---------------------------------------------------------------------------
// Launch
// ---------------------------------------------------------------------------
extern "C" void kernel_launch(void* const* d_in, const int* in_sizes, int n_in,
                              void* d_out, int out_size, void* d_ws, size_t ws_size,
                              hipStream_t stream) {
  const float* x    = (const float*)d_in[0];
  const float* Wq   = (const float*)d_in[1];
  const float* bq   = (const float*)d_in[2];
  const float* Wk   = (const float*)d_in[3];
  const float* bk   = (const float*)d_in[4];
  const float* Wv   = (const float*)d_in[5];
  const float* bv   = (const float*)d_in[6];
  const float* Wo   = (const float*)d_in[7];
  const float* bo   = (const float*)d_in[8];
  const float* iqW  = (const float*)d_in[9];
  const float* iqb  = (const float*)d_in[10];
  const float* ikW  = (const float*)d_in[11];
  const float* ikb  = (const float*)d_in[12];
  const float* wpW  = (const float*)d_in[13];
  const float* wpb  = (const float*)d_in[14];

  float* ws = (float*)d_ws;
  float* WI   = ws;                         // S*H fp32
  float* ISC  = WI + S * H;                 // S*S fp32
  unsigned* Mask = (unsigned*)(ISC + S * S);  // S*24
  float* Sum  = (float*)(Mask + S * 24);    // H*S
  float* ATTacc = Sum + H * S;              // S*E fp32 (atomic accumulator)
  unsigned short* u = (unsigned short*)(ATTacc + S * E);
  unsigned short* Xhi  = u;             u += S * E;
  unsigned short* Xlo  = u;             u += S * E;
  unsigned short* Qhi  = u;             u += S * E;
  unsigned short* Qlo  = u;             u += S * E;
  unsigned short* Khi  = u;             u += S * E;
  unsigned short* Klo  = u;             u += S * E;
  unsigned short* VThi = u;             u += S * E;
  unsigned short* QIhi = u;             u += S * E;
  unsigned short* QIlo = u;             u += S * E;
  unsigned short* KIhi = u;             u += S * DK;
  unsigned short* KIlo = u;             u += S * DK;
  unsigned short* WTq_hi = u;           u += E * E;
  unsigned short* WTk_hi = u;           u += E * E;
  unsigned short* WTv_hi = u;           u += E * E;
  unsigned short* WTiq_hi = u;          u += E * E;
  unsigned short* WTik_hi = u;          u += 64 * E;
  unsigned short* WTwp_hi = u;          u += 64 * E;
  unsigned short* WTo_hi = u;           u += E * E;
  unsigned short* WTq_lo = u;           u += E * E;
  unsigned short* WTk_lo = u;           u += E * E;
  unsigned short* WTv_lo = u;           u += E * E;
  unsigned short* WTiq_lo = u;          u += E * E;
  unsigned short* WTik_lo = u;          u += 64 * E;
  unsigned short* WTwp_lo = u;          u += 64 * E;
  unsigned short* WTo_lo = u;           u += E * E;

  PrepTab prep;
  prep.src[0] = x;    prep.hi[0] = Xhi;     prep.lo[0] = Xlo;
  prep.src[1] = Wq;   prep.hi[1] = WTq_hi;  prep.lo[1] = WTq_lo;
  prep.src[2] = Wk;   prep.hi[2] = WTk_hi;  prep.lo[2] = WTk_lo;
  prep.src[3] = Wv;   prep.hi[3] = WTv_hi;  prep.lo[3] = WTv_lo;
  prep.src[4] = iqW;  prep.hi[4] = WTiq_hi; prep.lo[4] = WTiq_lo;
  prep.src[5] = ikW;  prep.hi[5] = WTik_hi; prep.lo[5] = WTik_lo;
  prep.src[6] = wpW;  prep.hi[6] = WTwp_hi; prep.lo[6] = WTwp_lo;
  prep.src[7] = Wo;   prep.hi[7] = WTo_hi;  prep.lo[7] = WTo_lo;

  ProjTab pt;
  pt.whi[0] = WTq_hi;  pt.wlo[0] = WTq_lo;  pt.bias[0] = bq;
  pt.whi[1] = WTk_hi;  pt.wlo[1] = WTk_lo;  pt.bias[1] = bk;
  pt.whi[2] = WTv_hi;  pt.wlo[2] = WTv_lo;  pt.bias[2] = bv;
  pt.whi[3] = WTiq_hi; pt.wlo[3] = WTiq_lo; pt.bias[3] = iqb;
  pt.whi[4] = WTik_hi; pt.wlo[4] = WTik_lo; pt.bias[4] = ikb;
  pt.whi[5] = WTwp_hi; pt.wlo[5] = WTwp_lo; pt.bias[5] = wpb;

  // 1) split x + transpose/split all weight matrices
  prep_kernel<<<dim3(16, 24, 8), dim3(256), 0, stream>>>(prep);
  // 2) projections via MFMA, LDS chunk-staged
  proj_mfma_kernel<<<dim3(34, S / 64), dim3(256), 0, stream>>>(
      Xhi, Xlo, pt, Qhi, Qlo, Khi, Klo, VThi, QIhi, QIlo, KIhi, KIlo, WI);
  // 3) indexer via MFMA, LDS-staged QI per head-pair
  indexer_mfma_kernel<<<dim3(S / 64, S / 32), dim3(256), 0, stream>>>(
      QIhi, QIlo, KIhi, KIlo, WI, ISC);
  // 4) top-k per row (radix select; zeroes Sum and ATTacc)
  topk_kernel<<<dim3(S), dim3(256), 0, stream>>>(ISC, Mask, Sum, ATTacc);
  // 5) fused masked attention via MFMA, LDS-staged K/V, s-tile 64
  sattn_kernel<<<dim3(4, S / 64, H), dim3(512), 0, stream>>>(
      Qhi, Qlo, Khi, Klo, VThi, Mask, ATTacc, Sum);
  // 6) output projection (reads ATTacc+Sum; normalize+split in-register)
  out_mfma_kernel<<<dim3(8, 48), dim3(512), 0, stream>>>(
      ATTacc, Sum, WTo_hi, bo, (float*)d_out);
}

// Round 17
// 149.089 us; speedup vs baseline: 1.2535x; 1.0144x over previous
//
#include <hip/hip_runtime.h>
#include <hip/hip_bf16.h>
#include <math.h>

// Problem constants
#define S 768
#define E 512
#define H 8
#define DK 64
#define TOPK 384

typedef short bf16x8 __attribute__((ext_vector_type(8)));
typedef float f32x4 __attribute__((ext_vector_type(4)));

// ---------------------------------------------------------------------------
// fp32 <-> bf16 split helpers (round-to-nearest-even)
// ---------------------------------------------------------------------------
__device__ __forceinline__ unsigned short f2bf(float x) {
  unsigned u = __float_as_uint(x);
  unsigned r = u + 0x7FFFu + ((u >> 16) & 1u);
  return (unsigned short)(r >> 16);
}
__device__ __forceinline__ float bf2f(unsigned short h) {
  return __uint_as_float(((unsigned)h) << 16);
}
__device__ __forceinline__ void split1(float x, unsigned short& h, unsigned short& l) {
  h = f2bf(x);
  l = f2bf(x - bf2f(h));
}

// 3-term fp32-accurate bf16 MFMA
__device__ __forceinline__ void mfma3(f32x4& d, bf16x8 ah, bf16x8 al,
                                      bf16x8 bh, bf16x8 bl) {
  d = __builtin_amdgcn_mfma_f32_16x16x32_bf16(ah, bh, d, 0, 0, 0);
  d = __builtin_amdgcn_mfma_f32_16x16x32_bf16(ah, bl, d, 0, 0, 0);
  d = __builtin_amdgcn_mfma_f32_16x16x32_bf16(al, bh, d, 0, 0, 0);
}
// 2-term (B bf16-only)
__device__ __forceinline__ void mfma2(f32x4& d, bf16x8 ah, bf16x8 al, bf16x8 bh) {
  d = __builtin_amdgcn_mfma_f32_16x16x32_bf16(ah, bh, d, 0, 0, 0);
  d = __builtin_amdgcn_mfma_f32_16x16x32_bf16(al, bh, d, 0, 0, 0);
}

__device__ __forceinline__ bf16x8 ldfrag(const unsigned short* p) {
  return *reinterpret_cast<const bf16x8*>(p);
}

// ---------------------------------------------------------------------------
// prep (unchanged)
// ---------------------------------------------------------------------------
struct PrepTab {
  const float* src[8];
  unsigned short* hi[8];
  unsigned short* lo[8];
};

__global__ __launch_bounds__(256) void prep_kernel(PrepTab t) {
  const int seg = blockIdx.z;
  const int rows = (seg == 0) ? 768 : 512;
  const int cols = (seg == 5) ? 64 : ((seg == 6) ? 8 : 512);
  const int tx = (seg == 6) ? 2 : ((cols + 31) >> 5);
  const int ty = rows >> 5;
  if ((int)blockIdx.x >= tx || (int)blockIdx.y >= ty) return;
  const int r0 = blockIdx.y * 32, c0 = blockIdx.x * 32;
  const int tid = threadIdx.x;
  const int rl = tid >> 3, c4 = (tid & 7) << 2;
  const float* src = t.src[seg];
  if (seg == 0) {
    float4 v = *(const float4*)(src + (size_t)(r0 + rl) * cols + c0 + c4);
    unsigned short h[4], l[4];
    split1(v.x, h[0], l[0]); split1(v.y, h[1], l[1]);
    split1(v.z, h[2], l[2]); split1(v.w, h[3], l[3]);
    size_t off = (size_t)(r0 + rl) * cols + c0 + c4;
    *(ushort4*)(t.hi[seg] + off) = make_ushort4(h[0], h[1], h[2], h[3]);
    *(ushort4*)(t.lo[seg] + off) = make_ushort4(l[0], l[1], l[2], l[3]);
  } else {
    __shared__ float ts[32][33];
    #pragma unroll
    for (int j = 0; j < 4; ++j) {
      int c = c4 + j;
      ts[rl][c] = (c0 + c < cols) ? src[(size_t)(r0 + rl) * cols + c0 + c] : 0.0f;
    }
    __syncthreads();
    float v0 = ts[c4 + 0][rl], v1 = ts[c4 + 1][rl];
    float v2 = ts[c4 + 2][rl], v3 = ts[c4 + 3][rl];
    unsigned short h[4], l[4];
    split1(v0, h[0], l[0]); split1(v1, h[1], l[1]);
    split1(v2, h[2], l[2]); split1(v3, h[3], l[3]);
    size_t off = (size_t)(c0 + rl) * 512 + r0 + c4;
    *(ushort4*)(t.hi[seg] + off) = make_ushort4(h[0], h[1], h[2], h[3]);
    *(ushort4*)(t.lo[seg] + off) = make_ushort4(l[0], l[1], l[2], l[3]);
  }
}

// ---------------------------------------------------------------------------
// Fused projections via MFMA — LDS chunk-staged (unchanged from round 15).
// ---------------------------------------------------------------------------
struct ProjTab {
  const unsigned short* whi[6];
  const unsigned short* wlo[6];
  const float* bias[6];
};

__global__ __launch_bounds__(256) void proj_mfma_kernel(
    const unsigned short* __restrict__ Xhi, const unsigned short* __restrict__ Xlo,
    ProjTab pt,
    unsigned short* __restrict__ Qhi, unsigned short* __restrict__ Qlo,
    unsigned short* __restrict__ Khi, unsigned short* __restrict__ Klo,
    unsigned short* __restrict__ VThi,
    unsigned short* __restrict__ QIhi, unsigned short* __restrict__ QIlo,
    unsigned short* __restrict__ KIhi, unsigned short* __restrict__ KIlo,
    float* __restrict__ WI) {
  __shared__ __align__(16) unsigned short Ah[64][72];
  __shared__ __align__(16) unsigned short Al[64][72];
  __shared__ __align__(16) unsigned short Bh[64][72];
  __shared__ __align__(16) unsigned short Bl[64][72];
  const int bx = blockIdx.x;
  int seg, nt;
  if (bx < 32) { seg = bx >> 3; nt = bx & 7; }
  else         { seg = 4 + (bx - 32); nt = 0; }
  const int m0 = blockIdx.y * 64;
  const int n0 = nt * 64;
  const int tid = threadIdx.x;
  const int lane = tid & 63;
  const int wave = tid >> 6;
  const int mq = (wave >> 1) << 5;
  const int nq = (wave & 1) << 5;
  const int l15 = lane & 15;
  const int q8 = (lane >> 4) << 3;
  const int q4 = (lane >> 4) << 2;
  const unsigned short* Whi = pt.whi[seg];
  const unsigned short* Wlo = pt.wlo[seg];

  f32x4 acc[2][2] = {};
  for (int cc = 0; cc < 8; ++cc) {
    const int k0 = cc << 6;
    #pragma unroll
    for (int j = 0; j < 2; ++j) {
      const int flat = tid + (j << 8);
      const int mm = flat >> 3;
      const int kc = (flat & 7) << 3;
      const size_t ga = (size_t)(m0 + mm) * 512 + k0 + kc;
      const size_t gb = (size_t)(n0 + mm) * 512 + k0 + kc;
      *(bf16x8*)&Ah[mm][kc] = ldfrag(Xhi + ga);
      *(bf16x8*)&Al[mm][kc] = ldfrag(Xlo + ga);
      *(bf16x8*)&Bh[mm][kc] = ldfrag(Whi + gb);
      *(bf16x8*)&Bl[mm][kc] = ldfrag(Wlo + gb);
    }
    __syncthreads();
    #pragma unroll
    for (int ki = 0; ki < 64; ki += 32) {
      const int kk = ki + q8;
      bf16x8 ah0 = *(const bf16x8*)&Ah[mq + l15][kk];
      bf16x8 al0 = *(const bf16x8*)&Al[mq + l15][kk];
      bf16x8 ah1 = *(const bf16x8*)&Ah[mq + 16 + l15][kk];
      bf16x8 al1 = *(const bf16x8*)&Al[mq + 16 + l15][kk];
      bf16x8 bh0 = *(const bf16x8*)&Bh[nq + l15][kk];
      bf16x8 bl0 = *(const bf16x8*)&Bl[nq + l15][kk];
      bf16x8 bh1 = *(const bf16x8*)&Bh[nq + 16 + l15][kk];
      bf16x8 bl1 = *(const bf16x8*)&Bl[nq + 16 + l15][kk];
      mfma3(acc[0][0], ah0, al0, bh0, bl0);
      mfma3(acc[0][1], ah0, al0, bh1, bl1);
      mfma3(acc[1][0], ah1, al1, bh0, bl0);
      mfma3(acc[1][1], ah1, al1, bh1, bl1);
    }
    __syncthreads();
  }

  const float* bias = pt.bias[seg];
  #pragma unroll
  for (int ntt = 0; ntt < 2; ++ntt) {
    const int nloc = n0 + nq + ntt * 16 + l15;
    const float bv = (seg == 5 && nloc >= 8) ? 0.0f : bias[nloc];
    #pragma unroll
    for (int mt = 0; mt < 2; ++mt) {
      #pragma unroll
      for (int r = 0; r < 4; ++r) {
        const int m = m0 + mq + mt * 16 + q4 + r;
        const float v = acc[mt][ntt][r] + bv;
        unsigned short h16, l16;
        if (seg == 0) {
          split1(v, h16, l16);
          Qhi[(size_t)m * 512 + nloc] = h16;
          Qlo[(size_t)m * 512 + nloc] = l16;
        } else if (seg == 1) {
          const int hh = nloc >> 6, dd = nloc & 63;
          split1(v, h16, l16);
          Khi[((size_t)hh * S + m) * 64 + dd] = h16;
          Klo[((size_t)hh * S + m) * 64 + dd] = l16;
        } else if (seg == 2) {
          VThi[((size_t)(nloc >> 6) * 64 + (nloc & 63)) * S + m] = f2bf(v);
        } else if (seg == 3) {
          split1(v, h16, l16);
          QIhi[(size_t)m * 512 + nloc] = h16;
          QIlo[(size_t)m * 512 + nloc] = l16;
        } else if (seg == 4) {
          split1(v, h16, l16);
          KIhi[(size_t)m * 64 + nloc] = h16;
          KIlo[(size_t)m * 64 + nloc] = l16;
        } else {
          if (nloc < 8) WI[(size_t)m * 8 + nloc] = v;
        }
      }
    }
  }
}

// ---------------------------------------------------------------------------
// Indexer via MFMA — LDS-staged QI per head-pair (unchanged from round 16).
// ---------------------------------------------------------------------------
__global__ __launch_bounds__(256) void indexer_mfma_kernel(
    const unsigned short* __restrict__ QIhi, const unsigned short* __restrict__ QIlo,
    const unsigned short* __restrict__ KIhi, const unsigned short* __restrict__ KIlo,
    const float* __restrict__ WI, float* __restrict__ ISC) {
  __shared__ __align__(16) unsigned short Qh[32][136];
  __shared__ __align__(16) unsigned short Ql[32][136];
  __shared__ float wis[32][8];
  const int s0 = blockIdx.y * 32, t0 = blockIdx.x * 64;
  const int tid = threadIdx.x;
  const int lane = tid & 63;
  const int wave = tid >> 6;
  const int mq = (wave >> 1) << 4;
  const int nqb = (wave & 1) << 5;
  const int l15 = lane & 15;
  const int q8 = (lane >> 4) << 3;
  const int q4 = (lane >> 4) << 2;
  wis[tid >> 3][tid & 7] = WI[(size_t)(s0 + (tid >> 3)) * 8 + (tid & 7)];

  const size_t brow0 = (size_t)(t0 + nqb + l15) * 64;
  const size_t brow1 = (size_t)(t0 + nqb + 16 + l15) * 64;
  bf16x8 kfh[2][2], kfl[2][2];
  #pragma unroll
  for (int kk = 0; kk < 2; ++kk) {
    const int kb = kk * 32 + q8;
    kfh[kk][0] = ldfrag(KIhi + brow0 + kb);
    kfl[kk][0] = ldfrag(KIlo + brow0 + kb);
    kfh[kk][1] = ldfrag(KIhi + brow1 + kb);
    kfl[kk][1] = ldfrag(KIlo + brow1 + kb);
  }

  const int smm = tid >> 3;
  const int skc = (tid & 7) << 4;
  float accI[2][4] = {};
  for (int hp = 0; hp < 4; ++hp) {
    __syncthreads();
    {
      const size_t g = (size_t)(s0 + smm) * 512 + hp * 128 + skc;
      *(bf16x8*)&Qh[smm][skc]     = ldfrag(QIhi + g);
      *(bf16x8*)&Qh[smm][skc + 8] = ldfrag(QIhi + g + 8);
      *(bf16x8*)&Ql[smm][skc]     = ldfrag(QIlo + g);
      *(bf16x8*)&Ql[smm][skc + 8] = ldfrag(QIlo + g + 8);
    }
    __syncthreads();
    #pragma unroll
    for (int hh = 0; hh < 2; ++hh) {
      const int h = hp * 2 + hh;
      f32x4 d[2] = {};
      #pragma unroll
      for (int kk = 0; kk < 2; ++kk) {
        const int ka = hh * 64 + kk * 32 + q8;
        bf16x8 ah = *(const bf16x8*)&Qh[mq + l15][ka];
        bf16x8 al = *(const bf16x8*)&Ql[mq + l15][ka];
        mfma3(d[0], ah, al, kfh[kk][0], kfl[kk][0]);
        mfma3(d[1], ah, al, kfh[kk][1], kfl[kk][1]);
      }
      #pragma unroll
      for (int r = 0; r < 4; ++r) {
        const float w = wis[mq + q4 + r][h];
        accI[0][r] = fmaf(fmaxf(d[0][r], 0.0f), w, accI[0][r]);
        accI[1][r] = fmaf(fmaxf(d[1][r], 0.0f), w, accI[1][r]);
      }
    }
  }
  #pragma unroll
  for (int ntt = 0; ntt < 2; ++ntt)
    #pragma unroll
    for (int r = 0; r < 4; ++r)
      ISC[(size_t)(s0 + mq + q4 + r) * S + t0 + nqb + ntt * 16 + l15] = accI[ntt][r];
}

// ---------------------------------------------------------------------------
// Top-k via exact radix select; zeroes Sum and ATTacc (unchanged).
// ---------------------------------------------------------------------------
__global__ __launch_bounds__(256) void topk_kernel(
    const float* __restrict__ ISC, unsigned* __restrict__ Mask,
    float* __restrict__ Sum, float* __restrict__ ATTacc) {
  __shared__ unsigned ordv[768];
  __shared__ int hist[256];
  __shared__ int gsum[16];
  __shared__ int sc[256];
  __shared__ unsigned mw[24];
  __shared__ unsigned sh_prefix;
  __shared__ int sh_R;
  const int s = blockIdx.x;
  const int tid = threadIdx.x;
  for (int i = tid; i < 768; i += 256) {
    float f = ISC[s * 768 + i] + 0.0f;
    unsigned u = __float_as_uint(f);
    ordv[i] = (u & 0x80000000u) ? ~u : (u | 0x80000000u);
  }
  {
    const float4 z4 = {0.0f, 0.0f, 0.0f, 0.0f};
    if (tid < 128) *(float4*)(ATTacc + (size_t)s * 512 + tid * 4) = z4;
  }
  if (tid < 24) mw[tid] = 0u;
  if (tid < H) Sum[tid * S + s] = 0.0f;
  if (tid == 0) { sh_prefix = 0u; sh_R = TOPK; }
  __syncthreads();
  for (int pass = 0; pass < 4; ++pass) {
    const int shift = 24 - pass * 8;
    hist[tid] = 0;
    __syncthreads();
    const unsigned pm = (pass == 0) ? 0u : (0xFFFFFFFFu << (shift + 8));
    const unsigned pref = sh_prefix;
    for (int i = tid; i < 768; i += 256) {
      unsigned o = ordv[i];
      if ((o & pm) == pref) atomicAdd(&hist[(o >> shift) & 255], 1);
    }
    __syncthreads();
    if (tid < 16) {
      int t = 0;
      #pragma unroll
      for (int k = 0; k < 16; ++k) t += hist[tid * 16 + k];
      gsum[tid] = t;
    }
    __syncthreads();
    if (tid == 0) {
      int R = sh_R;
      int G = 0;
      int g = 15;
      for (; g > 0; --g) {
        if (G + gsum[g] >= R) break;
        G += gsum[g];
      }
      int b = 15;
      for (; b > 0; --b) {
        int c = hist[g * 16 + b];
        if (G + c >= R) break;
        G += c;
      }
      sh_prefix = sh_prefix | ((unsigned)(g * 16 + b) << shift);
      sh_R = R - G;
    }
    __syncthreads();
  }
  const unsigned thr = sh_prefix;
  const int need_eq = sh_R;
  const int base = tid * 3;
  unsigned o0 = ordv[base], o1 = ordv[base + 1], o2 = ordv[base + 2];
  int c = (o0 == thr) + (o1 == thr) + (o2 == thr);
  sc[tid] = c;
  __syncthreads();
  for (int off = 1; off < 256; off <<= 1) {
    int v = (tid >= off) ? sc[tid - off] : 0;
    __syncthreads();
    sc[tid] += v;
    __syncthreads();
  }
  int rank = sc[tid] - c;
  if (o0 > thr || (o0 == thr && rank < need_eq))
    atomicOr(&mw[base >> 5], 1u << (base & 31));
  if (o0 == thr) ++rank;
  if (o1 > thr || (o1 == thr && rank < need_eq))
    atomicOr(&mw[(base + 1) >> 5], 1u << ((base + 1) & 31));
  if (o1 == thr) ++rank;
  if (o2 > thr || (o2 == thr && rank < need_eq))
    atomicOr(&mw[(base + 2) >> 5], 1u << ((base + 2) & 31));
  __syncthreads();
  if (tid < 24) Mask[s * 24 + tid] = mw[tid];
}

// ---------------------------------------------------------------------------
// Fused masked attention via MFMA — 64-t chunks (3 per block, 9 barriers
// vs 18). 512 threads, s-tile 64. Per chunk: each thread stages 3 frags
// (Khi, Klo, V^T); each wave computes 2 column-quadrants of the 64x64
// score tile (QK 3-term), exp+mask, P->LDS, then PV 2-term over k=64.
// Direct fp32 atomics into ATTacc.
// ---------------------------------------------------------------------------
__global__ __launch_bounds__(512) void sattn_kernel(
    const unsigned short* __restrict__ Qhi, const unsigned short* __restrict__ Qlo,
    const unsigned short* __restrict__ Khi, const unsigned short* __restrict__ Klo,
    const unsigned short* __restrict__ VThi,
    const unsigned* __restrict__ Mask, float* __restrict__ ATTacc,
    float* __restrict__ Sum) {
  __shared__ __align__(16) unsigned short Ksh[64][72];
  __shared__ __align__(16) unsigned short Ksl[64][72];
  __shared__ __align__(16) unsigned short Vsh[64][72];
  __shared__ __align__(16) unsigned short Pshi[64][72];
  __shared__ __align__(16) unsigned short Pslo[64][72];
  __shared__ unsigned msk[64][6];
  __shared__ float rsumf[64];
  const int ks = blockIdx.x;
  const int s0 = blockIdx.y * 64;
  const int h  = blockIdx.z;
  const int tid = threadIdx.x;
  const int lane = tid & 63;
  const int wave = tid >> 6;          // 0..7
  const int l15 = lane & 15;
  const int q8 = (lane >> 4) << 3;
  const int q4 = (lane >> 4) << 2;
  const int mq = (wave >> 1) << 4;    // 0,16,32,48
  const int nqq = (wave & 1) << 4;    // 0 or 16 (column-quadrant base)
  const int db = (wave & 1) << 5;     // 0 or 32 (d-half for PV)

  if (tid < 384) msk[tid & 63][tid >> 6] =
      Mask[(size_t)(s0 + (tid & 63)) * 24 + ks * 6 + (tid >> 6)];
  if (tid < 64) rsumf[tid] = 0.0f;

  const size_t qrow = (size_t)(s0 + mq + l15) * 512 + h * 64;
  bf16x8 qh0 = ldfrag(Qhi + qrow + 0 + q8);
  bf16x8 ql0 = ldfrag(Qlo + qrow + 0 + q8);
  bf16x8 qh1 = ldfrag(Qhi + qrow + 32 + q8);
  bf16x8 ql1 = ldfrag(Qlo + qrow + 32 + q8);

  f32x4 oacc[2] = {};
  for (int ct = 0; ct < 3; ++ct) {
    const int tch = ks * 192 + ct * 64;
    __syncthreads();   // prev PV done reading Ksh/Vsh; first iter: msk ready
    {
      const int tr = tid >> 3;          // 0..63
      const int kc = (tid & 7) << 3;    // 0..56
      const size_t gk = ((size_t)h * S + tch + tr) * 64 + kc;
      *(bf16x8*)&Ksh[tr][kc] = ldfrag(Khi + gk);
      *(bf16x8*)&Ksl[tr][kc] = ldfrag(Klo + gk);
      *(bf16x8*)&Vsh[tr][kc] =
          ldfrag(VThi + ((size_t)h * 64 + tr) * S + tch + kc);
    }
    __syncthreads();
    // ---- QK from LDS: 2 column-quadrant passes per wave ----
    float esum[4] = {0.0f, 0.0f, 0.0f, 0.0f};
    #pragma unroll
    for (int cp = 0; cp < 2; ++cp) {
      const int tcol = nqq + cp * 32;   // 0,16,32,48
      f32x4 d = {0.0f, 0.0f, 0.0f, 0.0f};
      bf16x8 bh0 = *(const bf16x8*)&Ksh[tcol + l15][q8];
      bf16x8 bl0 = *(const bf16x8*)&Ksl[tcol + l15][q8];
      bf16x8 bh1 = *(const bf16x8*)&Ksh[tcol + l15][32 + q8];
      bf16x8 bl1 = *(const bf16x8*)&Ksl[tcol + l15][32 + q8];
      mfma3(d, qh0, ql0, bh0, bl0);
      mfma3(d, qh1, ql1, bh1, bl1);
      const int tl = ct * 64 + tcol + l15;
      #pragma unroll
      for (int r = 0; r < 4; ++r) {
        const int srow = mq + q4 + r;
        const unsigned w = msk[srow][tl >> 5];
        float e = ((w >> (tl & 31)) & 1u) ? __expf(d[r] * 0.125f) : 0.0f;
        unsigned short h16, l16;
        split1(e, h16, l16);
        Pshi[srow][tcol + l15] = h16;
        Pslo[srow][tcol + l15] = l16;
        esum[r] += e;
      }
    }
    float v0 = esum[0], v1 = esum[1], v2 = esum[2], v3 = esum[3];
    #pragma unroll
    for (int off = 1; off < 16; off <<= 1) {
      v0 += __shfl_xor(v0, off);
      v1 += __shfl_xor(v1, off);
      v2 += __shfl_xor(v2, off);
      v3 += __shfl_xor(v3, off);
    }
    if (l15 == 0) {
      atomicAdd(&rsumf[mq + q4 + 0], v0);
      atomicAdd(&rsumf[mq + q4 + 1], v1);
      atomicAdd(&rsumf[mq + q4 + 2], v2);
      atomicAdd(&rsumf[mq + q4 + 3], v3);
    }
    __syncthreads();
    // ---- PV from LDS: O[16s x 32d] += P[16s x 64t] * V^T[d][t] ----
    #pragma unroll
    for (int kk = 0; kk < 64; kk += 32) {
      bf16x8 pah = *(const bf16x8*)&Pshi[mq + l15][kk + q8];
      bf16x8 pal = *(const bf16x8*)&Pslo[mq + l15][kk + q8];
      #pragma unroll
      for (int dt = 0; dt < 2; ++dt) {
        bf16x8 vbh = *(const bf16x8*)&Vsh[db + dt * 16 + l15][kk + q8];
        mfma2(oacc[dt], pah, pal, vbh);
      }
    }
  }
  #pragma unroll
  for (int dt = 0; dt < 2; ++dt) {
    const int dd = db + dt * 16 + l15;
    #pragma unroll
    for (int r = 0; r < 4; ++r) {
      const int s = s0 + mq + q4 + r;
      atomicAdd(&ATTacc[(size_t)s * E + h * DK + dd], oacc[dt][r]);
    }
  }
  __syncthreads();
  if (tid < 64) atomicAdd(&Sum[(size_t)h * S + s0 + tid], rsumf[tid]);
}

// ---------------------------------------------------------------------------
// Output projection via MFMA (unchanged from round 15).
// ---------------------------------------------------------------------------
__global__ __launch_bounds__(512) void out_mfma_kernel(
    const float* __restrict__ ATTacc, const float* __restrict__ Sum,
    const unsigned short* __restrict__ WoThi,
    const float* __restrict__ bo, float* __restrict__ out) {
  __shared__ float AccL[16][65];
  __shared__ float ivs[16][8];
  const int tid512 = threadIdx.x;
  const int wave8 = tid512 >> 6;
  const int z = wave8 >> 2;
  const int wave = wave8 & 3;
  const int lane = tid512 & 63;
  const int m0 = blockIdx.y * 16;
  const int n0 = blockIdx.x * 64 + wave * 16;
  const int l15 = lane & 15;
  const int q8 = (lane >> 4) << 3;
  const int q4 = (lane >> 4) << 2;
  if (tid512 < 128) {
    const int r = tid512 >> 3, hh = tid512 & 7;
    ivs[r][hh] = 1.0f / Sum[(size_t)hh * S + m0 + r];
  }
  __syncthreads();
  const size_t arow = (size_t)(m0 + l15) * 512;
  const size_t brow = (size_t)(n0 + l15) * 512;
  int ko = (z << 8) + q8;
  bf16x8 cah, cal;
  {
    const float inv0 = ivs[l15][(ko >> 6) & 7];
    float4 a = *(const float4*)(ATTacc + arow + ko);
    float4 b = *(const float4*)(ATTacc + arow + ko + 4);
    float v[8] = {a.x, a.y, a.z, a.w, b.x, b.y, b.z, b.w};
    #pragma unroll
    for (int i = 0; i < 8; ++i) {
      unsigned short hh, ll;
      split1(v[i] * inv0, hh, ll);
      cah[i] = (short)hh; cal[i] = (short)ll;
    }
  }
  bf16x8 cbh = ldfrag(WoThi + brow + ko);
  f32x4 acc = {};
  #pragma unroll
  for (int it = 0; it < 8; ++it) {
    const int kn = ko + 32;
    float4 na = *(const float4*)(ATTacc + arow + kn);
    float4 nb = *(const float4*)(ATTacc + arow + kn + 4);
    bf16x8 nbh = ldfrag(WoThi + brow + kn);
    mfma2(acc, cah, cal, cbh);
    const float invn = ivs[l15][(kn >> 6) & 7];
    float v[8] = {na.x, na.y, na.z, na.w, nb.x, nb.y, nb.z, nb.w};
    #pragma unroll
    for (int i = 0; i < 8; ++i) {
      unsigned short hh, ll;
      split1(v[i] * invn, hh, ll);
      cah[i] = (short)hh; cal[i] = (short)ll;
    }
    cbh = nbh;
    ko = kn;
  }
  if (z == 1) {
    #pragma unroll
    for (int r = 0; r < 4; ++r)
      AccL[q4 + r][wave * 16 + l15] = acc[r];
  }
  __syncthreads();
  if (z == 0) {
    const int n = n0 + l15;
    const float bv = bo[n];
    #pragma unroll
    for (int r = 0; r < 4; ++r)
      out[(size_t)(m0 + q4 + r) * 512 + n] =
          acc[r] + AccL[q4 + r][wave * 16 + l15] + bv;
  }
}

// ---------------------------------------------------------------------------
// Launch
// ---------------------------------------------------------------------------
extern "C" void kernel_launch(void* const* d_in, const int* in_sizes, int n_in,
                              void* d_out, int out_size, void* d_ws, size_t ws_size,
                              hipStream_t stream) {
  const float* x    = (const float*)d_in[0];
  const float* Wq   = (const float*)d_in[1];
  const float* bq   = (const float*)d_in[2];
  const float* Wk   = (const float*)d_in[3];
  const float* bk   = (const float*)d_in[4];
  const float* Wv   = (const float*)d_in[5];
  const float* bv   = (const float*)d_in[6];
  const float* Wo   = (const float*)d_in[7];
  const float* bo   = (const float*)d_in[8];
  const float* iqW  = (const float*)d_in[9];
  const float* iqb  = (const float*)d_in[10];
  const float* ikW  = (const float*)d_in[11];
  const float* ikb  = (const float*)d_in[12];
  const float* wpW  = (const float*)d_in[13];
  const float* wpb  = (const float*)d_in[14];

  float* ws = (float*)d_ws;
  float* WI   = ws;                         // S*H fp32
  float* ISC  = WI + S * H;                 // S*S fp32
  unsigned* Mask = (unsigned*)(ISC + S * S);  // S*24
  float* Sum  = (float*)(Mask + S * 24);    // H*S
  float* ATTacc = Sum + H * S;              // S*E fp32 (atomic accumulator)
  unsigned short* u = (unsigned short*)(ATTacc + S * E);
  unsigned short* Xhi  = u;             u += S * E;
  unsigned short* Xlo  = u;             u += S * E;
  unsigned short* Qhi  = u;             u += S * E;
  unsigned short* Qlo  = u;             u += S * E;
  unsigned short* Khi  = u;             u += S * E;
  unsigned short* Klo  = u;             u += S * E;
  unsigned short* VThi = u;             u += S * E;
  unsigned short* QIhi = u;             u += S * E;
  unsigned short* QIlo = u;             u += S * E;
  unsigned short* KIhi = u;             u += S * DK;
  unsigned short* KIlo = u;             u += S * DK;
  unsigned short* WTq_hi = u;           u += E * E;
  unsigned short* WTk_hi = u;           u += E * E;
  unsigned short* WTv_hi = u;           u += E * E;
  unsigned short* WTiq_hi = u;          u += E * E;
  unsigned short* WTik_hi = u;          u += 64 * E;
  unsigned short* WTwp_hi = u;          u += 64 * E;
  unsigned short* WTo_hi = u;           u += E * E;
  unsigned short* WTq_lo = u;           u += E * E;
  unsigned short* WTk_lo = u;           u += E * E;
  unsigned short* WTv_lo = u;           u += E * E;
  unsigned short* WTiq_lo = u;          u += E * E;
  unsigned short* WTik_lo = u;          u += 64 * E;
  unsigned short* WTwp_lo = u;          u += 64 * E;
  unsigned short* WTo_lo = u;           u += E * E;

  PrepTab prep;
  prep.src[0] = x;    prep.hi[0] = Xhi;     prep.lo[0] = Xlo;
  prep.src[1] = Wq;   prep.hi[1] = WTq_hi;  prep.lo[1] = WTq_lo;
  prep.src[2] = Wk;   prep.hi[2] = WTk_hi;  prep.lo[2] = WTk_lo;
  prep.src[3] = Wv;   prep.hi[3] = WTv_hi;  prep.lo[3] = WTv_lo;
  prep.src[4] = iqW;  prep.hi[4] = WTiq_hi; prep.lo[4] = WTiq_lo;
  prep.src[5] = ikW;  prep.hi[5] = WTik_hi; prep.lo[5] = WTik_lo;
  prep.src[6] = wpW;  prep.hi[6] = WTwp_hi; prep.lo[6] = WTwp_lo;
  prep.src[7] = Wo;   prep.hi[7] = WTo_hi;  prep.lo[7] = WTo_lo;

  ProjTab pt;
  pt.whi[0] = WTq_hi;  pt.wlo[0] = WTq_lo;  pt.bias[0] = bq;
  pt.whi[1] = WTk_hi;  pt.wlo[1] = WTk_lo;  pt.bias[1] = bk;
  pt.whi[2] = WTv_hi;  pt.wlo[2] = WTv_lo;  pt.bias[2] = bv;
  pt.whi[3] = WTiq_hi; pt.wlo[3] = WTiq_lo; pt.bias[3] = iqb;
  pt.whi[4] = WTik_hi; pt.wlo[4] = WTik_lo; pt.bias[4] = ikb;
  pt.whi[5] = WTwp_hi; pt.wlo[5] = WTwp_lo; pt.bias[5] = wpb;

  // 1) split x + transpose/split all weight matrices
  prep_kernel<<<dim3(16, 24, 8), dim3(256), 0, stream>>>(prep);
  // 2) projections via MFMA, LDS chunk-staged
  proj_mfma_kernel<<<dim3(34, S / 64), dim3(256), 0, stream>>>(
      Xhi, Xlo, pt, Qhi, Qlo, Khi, Klo, VThi, QIhi, QIlo, KIhi, KIlo, WI);
  // 3) indexer via MFMA, LDS-staged QI per head-pair
  indexer_mfma_kernel<<<dim3(S / 64, S / 32), dim3(256), 0, stream>>>(
      QIhi, QIlo, KIhi, KIlo, WI, ISC);
  // 4) top-k per row (radix select; zeroes Sum and ATTacc)
  topk_kernel<<<dim3(S), dim3(256), 0, stream>>>(ISC, Mask, Sum, ATTacc);
  // 5) fused masked attention via MFMA, 64-t LDS chunks
  sattn_kernel<<<dim3(4, S / 64, H), dim3(512), 0, stream>>>(
      Qhi, Qlo, Khi, Klo, VThi, Mask, ATTacc, Sum);
  // 6) output projection (reads ATTacc+Sum; normalize+split in-register)
  out_mfma_kernel<<<dim3(8, 48), dim3(512), 0, stream>>>(
      ATTacc, Sum, WTo_hi, bo, (float*)d_out);
}